// Round 1
// baseline (755.981 us; speedup 1.0000x reference)
//
#include <hip/hip_runtime.h>
#include <hip/hip_bf16.h>

// GATNet: 2-layer GAT, N=50000, E=800000 (+N self loops), fp32.
// Pipeline: CSR build (hist/scan/scatter) -> GEMM1 -> attention logits ->
// per-dst softmax-aggregate (layer1) -> GEMM2+logits -> aggregate+log_softmax.

#define LRELU(x) ((x) > 0.f ? (x) : 0.2f * (x))

// ---------------- CSR build ----------------

__global__ void k_init_deg(int* deg, int n) {
    int i = blockIdx.x * blockDim.x + threadIdx.x;
    if (i < n) deg[i] = 1;  // self loop
}

__global__ void k_hist(const int* __restrict__ dst, int* deg, int E) {
    int i = blockIdx.x * blockDim.x + threadIdx.x;
    if (i < E) atomicAdd(&deg[dst[i]], 1);
}

__global__ __launch_bounds__(1024) void k_scan(const int* __restrict__ deg,
                                               int* __restrict__ offs,
                                               int* __restrict__ cursor, int n) {
    __shared__ int sc[1024];
    int t = threadIdx.x;
    int CH = (n + 1023) / 1024;
    int s = t * CH;
    int e = min(s + CH, n);
    int sum = 0;
    for (int i = s; i < e; ++i) sum += deg[i];
    sc[t] = sum;
    __syncthreads();
    // Hillis-Steele inclusive scan
    for (int off = 1; off < 1024; off <<= 1) {
        int v = 0;
        if (t >= off) v = sc[t - off];
        __syncthreads();
        sc[t] += v;
        __syncthreads();
    }
    int excl = sc[t] - sum;
    int run = excl;
    for (int i = s; i < e; ++i) {
        offs[i] = run;
        cursor[i] = run;
        run += deg[i];
    }
    if (t == 1023) offs[n] = sc[1023];
}

__global__ void k_scatter(const int* __restrict__ src, const int* __restrict__ dst,
                          int* cursor, int* __restrict__ csr, int E, int n) {
    int i = blockIdx.x * blockDim.x + threadIdx.x;
    int s, d;
    if (i < E) {
        s = src[i];
        d = dst[i];
    } else if (i < E + n) {
        s = i - E;
        d = s;
    } else {
        return;
    }
    int p = atomicAdd(&cursor[d], 1);
    csr[p] = s;
}

// ---------------- GEMM1: [M,256] @ [256,256] -> h1 ----------------

__global__ __launch_bounds__(256) void k_gemm1(const float* __restrict__ A,
                                               const float* __restrict__ B,
                                               float* __restrict__ C, int M) {
    const int K = 256, N = 256;
    __shared__ float As[64][17];
    __shared__ float Bs[16][64];
    int t = threadIdx.x;
    int tx = t & 15, ty = t >> 4;
    int row0 = blockIdx.x * 64;
    int col0 = blockIdx.y * 64;
    float c[4][4] = {};
    for (int k0 = 0; k0 < K; k0 += 16) {
#pragma unroll
        for (int s = 0; s < 4; s++) {
            int l = t + s * 256;
            int m = l >> 4, k = l & 15;
            int row = row0 + m;
            As[m][k] = (row < M) ? A[row * K + k0 + k] : 0.f;
        }
#pragma unroll
        for (int s = 0; s < 4; s++) {
            int l = t + s * 256;
            int k = l >> 6, j = l & 63;
            Bs[k][j] = B[(k0 + k) * N + col0 + j];
        }
        __syncthreads();
#pragma unroll
        for (int kk = 0; kk < 16; kk++) {
            float a[4], b[4];
#pragma unroll
            for (int i = 0; i < 4; i++) a[i] = As[ty * 4 + i][kk];
#pragma unroll
            for (int j = 0; j < 4; j++) b[j] = Bs[kk][tx * 4 + j];
#pragma unroll
            for (int i = 0; i < 4; i++)
#pragma unroll
                for (int j = 0; j < 4; j++) c[i][j] += a[i] * b[j];
        }
        __syncthreads();
    }
#pragma unroll
    for (int i = 0; i < 4; i++) {
        int row = row0 + ty * 4 + i;
        if (row < M) {
            float4 v = make_float4(c[i][0], c[i][1], c[i][2], c[i][3]);
            *(float4*)&C[row * N + col0 + tx * 4] = v;
        }
    }
}

// ---------------- attention logits layer 1 ----------------
// al_s[v,h] = sum_c h1[v,h*32+c]*a_src[h*32+c]  (one block per node)

__global__ __launch_bounds__(256) void k_al1(const float* __restrict__ h1,
                                             const float* __restrict__ asrc,
                                             const float* __restrict__ adst,
                                             float* __restrict__ als,
                                             float* __restrict__ ald) {
    int v = blockIdx.x, t = threadIdx.x;
    float hv = h1[v * 256 + t];
    float ps = hv * asrc[t], pd = hv * adst[t];
#pragma unroll
    for (int off = 16; off; off >>= 1) {
        ps += __shfl_down(ps, off, 32);
        pd += __shfl_down(pd, off, 32);
    }
    if ((t & 31) == 0) {
        int h = t >> 5;
        als[v * 8 + h] = ps;
        ald[v * 8 + h] = pd;
    }
}

// ---------------- layer-1 softmax aggregate (block per dst node) ----------------

__global__ __launch_bounds__(256) void k_agg1(const int* __restrict__ csr,
                                              const int* __restrict__ offs,
                                              const float* __restrict__ als,
                                              const float* __restrict__ aldg,
                                              const float* __restrict__ h1,
                                              const float* __restrict__ b1,
                                              float* __restrict__ x2) {
    int v = blockIdx.x;
    int t = threadIdx.x;
    int start = offs[v];
    int deg = offs[v + 1] - start;
    __shared__ float ald[8];
    __shared__ float red[4 * 8];
    __shared__ float mh[8], invd[8];
    __shared__ int su[256];
    __shared__ float wsh[256 * 8];
    if (t < 8) ald[t] = aldg[v * 8 + t];
    __syncthreads();

    // phase A: per-head max over incoming edges
    float tv[8];
#pragma unroll
    for (int h = 0; h < 8; h++) tv[h] = -1e30f;
    for (int e = t; e < deg; e += 256) {
        int u = csr[start + e];
        const float4* as4 = (const float4*)(als + u * 8);
        float4 a0 = as4[0], a1 = as4[1];
        float av[8] = {a0.x, a0.y, a0.z, a0.w, a1.x, a1.y, a1.z, a1.w};
#pragma unroll
        for (int h = 0; h < 8; h++) {
            float x = av[h] + ald[h];
            x = LRELU(x);
            tv[h] = fmaxf(tv[h], x);
        }
    }
#pragma unroll
    for (int h = 0; h < 8; h++) {
        float m = tv[h];
        for (int off = 32; off; off >>= 1) m = fmaxf(m, __shfl_down(m, off, 64));
        if ((t & 63) == 0) red[(t >> 6) * 8 + h] = m;
    }
    __syncthreads();
    if (t < 8) mh[t] = fmaxf(fmaxf(red[t], red[8 + t]), fmaxf(red[16 + t], red[24 + t]));
    __syncthreads();

    // phase A2: denominator
    float ts[8];
#pragma unroll
    for (int h = 0; h < 8; h++) ts[h] = 0.f;
    for (int e = t; e < deg; e += 256) {
        int u = csr[start + e];
        const float4* as4 = (const float4*)(als + u * 8);
        float4 a0 = as4[0], a1 = as4[1];
        float av[8] = {a0.x, a0.y, a0.z, a0.w, a1.x, a1.y, a1.z, a1.w};
#pragma unroll
        for (int h = 0; h < 8; h++) {
            float x = av[h] + ald[h];
            x = LRELU(x);
            ts[h] += __expf(x - mh[h]);
        }
    }
    __syncthreads();  // red reuse
#pragma unroll
    for (int h = 0; h < 8; h++) {
        float s = ts[h];
        for (int off = 32; off; off >>= 1) s += __shfl_down(s, off, 64);
        if ((t & 63) == 0) red[(t >> 6) * 8 + h] = s;
    }
    __syncthreads();
    if (t < 8) invd[t] = 1.0f / (red[t] + red[8 + t] + red[16 + t] + red[24 + t]);
    __syncthreads();

    // phase B: weighted aggregation, chunked through LDS
    int h = t >> 5;
    float acc = 0.f;
    for (int base = 0; base < deg; base += 256) {
        int cnt = min(256, deg - base);
        __syncthreads();
        if (t < cnt) {
            int u = csr[start + base + t];
            su[t] = u;
            const float4* as4 = (const float4*)(als + u * 8);
            float4 a0 = as4[0], a1 = as4[1];
            float av[8] = {a0.x, a0.y, a0.z, a0.w, a1.x, a1.y, a1.z, a1.w};
#pragma unroll
            for (int hh = 0; hh < 8; hh++) {
                float x = av[hh] + ald[hh];
                x = LRELU(x);
                wsh[t * 8 + hh] = __expf(x - mh[hh]) * invd[hh];
            }
        }
        __syncthreads();
#pragma unroll 4
        for (int e = 0; e < cnt; e++) {
            acc += wsh[e * 8 + h] * h1[su[e] * 256 + t];
        }
    }
    float o = acc + b1[t];
    x2[v * 256 + t] = o > 0.f ? o : 0.f;
}

// ---------------- GEMM2 + layer-2 logits: [M,256]@[256,16] ----------------

__global__ __launch_bounds__(256) void k_gemm2(const float* __restrict__ X,
                                               const float* __restrict__ W,
                                               const float* __restrict__ asrc,
                                               const float* __restrict__ adst,
                                               float* __restrict__ h2,
                                               float* __restrict__ als,
                                               float* __restrict__ ald, int n) {
    __shared__ float xs[16][260];
    __shared__ float ws[256 * 16];
    int t = threadIdx.x;
    int r0 = blockIdx.x * 16;
#pragma unroll
    for (int i = 0; i < 16; i++) ws[t + i * 256] = W[t + i * 256];
#pragma unroll
    for (int i = 0; i < 16; i++) {
        int row = r0 + i;
        xs[i][t] = (row < n) ? X[row * 256 + t] : 0.f;
    }
    __syncthreads();
    int nl = t >> 4, j = t & 15;
    float acc = 0.f;
    const float4* xv = (const float4*)&xs[nl][0];
#pragma unroll 8
    for (int k4 = 0; k4 < 64; k4++) {
        float4 a = xv[k4];
        int k = k4 * 4;
        acc += a.x * ws[k * 16 + j] + a.y * ws[(k + 1) * 16 + j] +
               a.z * ws[(k + 2) * 16 + j] + a.w * ws[(k + 3) * 16 + j];
    }
    int row = r0 + nl;
    float ps = acc * asrc[j], pd = acc * adst[j];
#pragma unroll
    for (int off = 8; off; off >>= 1) {
        ps += __shfl_down(ps, off, 16);
        pd += __shfl_down(pd, off, 16);
    }
    if (row < n) {
        h2[row * 16 + j] = acc;
        if (j == 0) {
            als[row] = ps;
            ald[row] = pd;
        }
    }
}

// ---------------- layer-2 aggregate + log_softmax (wave per node) ----------------

__global__ __launch_bounds__(64) void k_agg2(const int* __restrict__ csr,
                                             const int* __restrict__ offs,
                                             const float* __restrict__ als,
                                             const float* __restrict__ aldg,
                                             const float* __restrict__ h2,
                                             const float* __restrict__ b2,
                                             float* __restrict__ out) {
    int v = blockIdx.x;
    int lane = threadIdx.x;
    int start = offs[v];
    int deg = offs[v + 1] - start;
    float ald = aldg[v];

    float tmax = -1e30f;
    for (int e = lane; e < deg; e += 64) {
        float x = als[csr[start + e]] + ald;
        x = LRELU(x);
        tmax = fmaxf(tmax, x);
    }
    for (int off = 32; off; off >>= 1) tmax = fmaxf(tmax, __shfl_xor(tmax, off, 64));
    float m = tmax;

    float tsum = 0.f;
    for (int e = lane; e < deg; e += 64) {
        float x = als[csr[start + e]] + ald;
        x = LRELU(x);
        tsum += __expf(x - m);
    }
    for (int off = 32; off; off >>= 1) tsum += __shfl_xor(tsum, off, 64);
    float inv = 1.0f / tsum;

    __shared__ int su[64];
    __shared__ float w[64];
    int c = lane & 15, q = lane >> 4;
    float acc = 0.f;
    for (int base = 0; base < deg; base += 64) {
        int cnt = min(64, deg - base);
        __syncthreads();
        if (lane < cnt) {
            int u = csr[start + base + lane];
            su[lane] = u;
            float x = als[u] + ald;
            x = LRELU(x);
            w[lane] = __expf(x - m) * inv;
        }
        __syncthreads();
        for (int e = q; e < cnt; e += 4) {
            acc += w[e] * h2[su[e] * 16 + c];
        }
    }
    acc += __shfl_down(acc, 32, 64);
    acc += __shfl_down(acc, 16, 64);
    float o = acc + b2[c];
    float mx = o;
#pragma unroll
    for (int off = 8; off; off >>= 1) mx = fmaxf(mx, __shfl_xor(mx, off, 16));
    float s = __expf(o - mx);
#pragma unroll
    for (int off = 8; off; off >>= 1) s += __shfl_xor(s, off, 16);
    float res = o - mx - __logf(s);
    if (lane < 16) out[v * 16 + lane] = res;
}

// ---------------- launch ----------------

extern "C" void kernel_launch(void* const* d_in, const int* in_sizes, int n_in,
                              void* d_out, int out_size, void* d_ws, size_t ws_size,
                              hipStream_t stream) {
    const float* x = (const float*)d_in[0];
    const int* ei = (const int*)d_in[1];
    const float* W1 = (const float*)d_in[2];
    const float* asrc1 = (const float*)d_in[3];
    const float* adst1 = (const float*)d_in[4];
    const float* b1 = (const float*)d_in[5];
    const float* W2 = (const float*)d_in[6];
    const float* asrc2 = (const float*)d_in[7];
    const float* adst2 = (const float*)d_in[8];
    const float* b2 = (const float*)d_in[9];
    float* out = (float*)d_out;

    int n = in_sizes[0] / 256;   // 50000
    int E = in_sizes[1] / 2;     // 800000
    const int* src = ei;
    const int* dst = ei + E;

    char* p = (char*)d_ws;
    auto alloc = [&](size_t bytes) {
        void* r = (void*)p;
        p += (bytes + 255) & ~(size_t)255;
        return r;
    };
    float* h1 = (float*)alloc((size_t)n * 256 * 4);
    float* x2 = (float*)alloc((size_t)n * 256 * 4);
    float* als1 = (float*)alloc((size_t)n * 8 * 4);
    float* ald1 = (float*)alloc((size_t)n * 8 * 4);
    float* h2 = (float*)alloc((size_t)n * 16 * 4);
    float* als2 = (float*)alloc((size_t)n * 4);
    float* ald2 = (float*)alloc((size_t)n * 4);
    int* deg = (int*)alloc((size_t)n * 4);
    int* offs = (int*)alloc((size_t)(n + 1) * 4);
    int* cursor = (int*)alloc((size_t)n * 4);
    int* csr = (int*)alloc((size_t)(E + n) * 4);

    // CSR build
    k_init_deg<<<(n + 255) / 256, 256, 0, stream>>>(deg, n);
    k_hist<<<(E + 255) / 256, 256, 0, stream>>>(dst, deg, E);
    k_scan<<<1, 1024, 0, stream>>>(deg, offs, cursor, n);
    k_scatter<<<(E + n + 255) / 256, 256, 0, stream>>>(src, dst, cursor, csr, E, n);

    // layer 1
    k_gemm1<<<dim3((n + 63) / 64, 4), 256, 0, stream>>>(x, W1, h1, n);
    k_al1<<<n, 256, 0, stream>>>(h1, asrc1, adst1, als1, ald1);
    k_agg1<<<n, 256, 0, stream>>>(csr, offs, als1, ald1, h1, b1, x2);

    // layer 2
    k_gemm2<<<(n + 15) / 16, 256, 0, stream>>>(x2, W2, asrc2, adst2, h2, als2, ald2, n);
    k_agg2<<<n, 64, 0, stream>>>(csr, offs, als2, ald2, h2, b2, out);
}

// Round 2
// 611.467 us; speedup vs baseline: 1.2363x; 1.2363x over previous
//
#include <hip/hip_runtime.h>
#include <hip/hip_bf16.h>

// GATNet: 2-layer GAT, N=50000, E=800000 (+N self loops), fp32.
// v2: edge-parallel softmax-weight precompute (no max subtraction; logits are
// O(1) so exp cannot overflow and softmax is shift-invariant), single-pass
// aggregation kernels, vectorized-LDS fp32 GEMM1.

#define LRELU(x) ((x) > 0.f ? (x) : 0.2f * (x))

// ---------------- CSR build ----------------

__global__ void k_init_deg(int* deg, int n) {
    int i = blockIdx.x * blockDim.x + threadIdx.x;
    if (i < n) deg[i] = 1;  // self loop
}

__global__ void k_hist(const int* __restrict__ dst, int* deg, int E) {
    int i = blockIdx.x * blockDim.x + threadIdx.x;
    if (i < E) atomicAdd(&deg[dst[i]], 1);
}

__global__ __launch_bounds__(1024) void k_scan(const int* __restrict__ deg,
                                               int* __restrict__ offs,
                                               int* __restrict__ cursor, int n) {
    __shared__ int sc[1024];
    int t = threadIdx.x;
    int CH = (n + 1023) / 1024;
    int s = t * CH;
    int e = min(s + CH, n);
    int sum = 0;
    for (int i = s; i < e; ++i) sum += deg[i];
    sc[t] = sum;
    __syncthreads();
    for (int off = 1; off < 1024; off <<= 1) {
        int v = 0;
        if (t >= off) v = sc[t - off];
        __syncthreads();
        sc[t] += v;
        __syncthreads();
    }
    int excl = sc[t] - sum;
    int run = excl;
    for (int i = s; i < e; ++i) {
        offs[i] = run;
        cursor[i] = run;
        run += deg[i];
    }
    if (t == 1023) offs[n] = sc[1023];
}

__global__ void k_scatter(const int* __restrict__ src, const int* __restrict__ dst,
                          int* cursor, int* __restrict__ csr, int* __restrict__ dstv,
                          int E, int n) {
    int i = blockIdx.x * blockDim.x + threadIdx.x;
    int s, d;
    if (i < E) {
        s = src[i];
        d = dst[i];
    } else if (i < E + n) {
        s = i - E;
        d = s;
    } else {
        return;
    }
    int p = atomicAdd(&cursor[d], 1);
    csr[p] = s;
    dstv[p] = d;
}

// ---------------- GEMM1: [M,256] @ [256,256] -> h1 ----------------
// 64x64 tile, 4x4/thread, k-major A tile (pad 68 floats = 272 B: 16B-aligned
// rows, 2-way-free bank pattern), float4 LDS reads in the inner loop.

__global__ __launch_bounds__(256) void k_gemm1(const float* __restrict__ A,
                                               const float* __restrict__ B,
                                               float* __restrict__ C, int M) {
    __shared__ float As[16][68];
    __shared__ float Bs[16][64];
    int t = threadIdx.x;
    int tx = t & 15, ty = t >> 4;
    int row0 = blockIdx.x * 64, col0 = blockIdx.y * 64;
    int arow = t >> 2, akq = t & 3;   // A stage: 64 rows x 4 float4
    int bk = t >> 4, bjq = t & 15;    // B stage: 16 k x 16 float4
    float c[4][4] = {};
    for (int k0 = 0; k0 < 256; k0 += 16) {
        float4 av = make_float4(0.f, 0.f, 0.f, 0.f);
        if (row0 + arow < M) av = *(const float4*)&A[(size_t)(row0 + arow) * 256 + k0 + akq * 4];
        float4 bv = *(const float4*)&B[(size_t)(bk + k0) * 256 + col0 + bjq * 4];
        if (k0) __syncthreads();
        As[akq * 4 + 0][arow] = av.x;
        As[akq * 4 + 1][arow] = av.y;
        As[akq * 4 + 2][arow] = av.z;
        As[akq * 4 + 3][arow] = av.w;
        *(float4*)&Bs[bk][bjq * 4] = bv;
        __syncthreads();
#pragma unroll
        for (int kk = 0; kk < 16; kk++) {
            float4 a4 = *(const float4*)&As[kk][ty * 4];
            float4 b4 = *(const float4*)&Bs[kk][tx * 4];
            float a[4] = {a4.x, a4.y, a4.z, a4.w};
            float b[4] = {b4.x, b4.y, b4.z, b4.w};
#pragma unroll
            for (int i = 0; i < 4; i++)
#pragma unroll
                for (int j = 0; j < 4; j++) c[i][j] += a[i] * b[j];
        }
    }
#pragma unroll
    for (int i = 0; i < 4; i++) {
        int row = row0 + ty * 4 + i;
        if (row < M) {
            float4 v = make_float4(c[i][0], c[i][1], c[i][2], c[i][3]);
            *(float4*)&C[(size_t)row * 256 + col0 + tx * 4] = v;
        }
    }
}

// ---------------- attention logits layer 1 ----------------

__global__ __launch_bounds__(256) void k_al1(const float* __restrict__ h1,
                                             const float* __restrict__ asrc,
                                             const float* __restrict__ adst,
                                             float* __restrict__ als,
                                             float* __restrict__ ald) {
    int v = blockIdx.x, t = threadIdx.x;
    float hv = h1[(size_t)v * 256 + t];
    float ps = hv * asrc[t], pd = hv * adst[t];
#pragma unroll
    for (int off = 16; off; off >>= 1) {
        ps += __shfl_down(ps, off, 32);
        pd += __shfl_down(pd, off, 32);
    }
    if ((t & 31) == 0) {
        int h = t >> 5;
        als[v * 8 + h] = ps;
        ald[v * 8 + h] = pd;
    }
}

// ---------------- edge-parallel weight precompute ----------------
// w1[p*8+h] = exp(lrelu(als[csr[p]*8+h] + ald[dstv[p]*8+h])), CSR-slot order.

__global__ void k_w1(const int* __restrict__ csr, const int* __restrict__ dstv,
                     const float* __restrict__ als, const float* __restrict__ ald,
                     float* __restrict__ w, int P) {
    int i = blockIdx.x * blockDim.x + threadIdx.x;
    if (i >= P * 8) return;
    int p = i >> 3, h = i & 7;
    int u = csr[p], d = dstv[p];
    float x = als[u * 8 + h] + ald[d * 8 + h];
    w[i] = __expf(LRELU(x));
}

__global__ void k_w2(const int* __restrict__ csr, const int* __restrict__ dstv,
                     const float* __restrict__ als, const float* __restrict__ ald,
                     float* __restrict__ w, int P) {
    int p = blockIdx.x * blockDim.x + threadIdx.x;
    if (p >= P) return;
    float x = als[csr[p]] + ald[dstv[p]];
    w[p] = __expf(LRELU(x));
}

// ---------------- layer-1 aggregate: single pass, num+denom together ----------

__global__ __launch_bounds__(256) void k_agg1(const int* __restrict__ csr,
                                              const int* __restrict__ offs,
                                              const float* __restrict__ w1,
                                              const float* __restrict__ h1,
                                              const float* __restrict__ b1,
                                              float* __restrict__ x2) {
    int v = blockIdx.x;
    int t = threadIdx.x;
    int start = offs[v];
    int deg = offs[v + 1] - start;
    __shared__ int su[32];
    __shared__ float ws[256];
    int h = t >> 5;
    float acc = 0.f, wsum = 0.f;
    for (int base = 0; base < deg; base += 32) {
        int cnt = min(32, deg - base);
        if (base) __syncthreads();
        if (t < cnt) su[t] = csr[start + base + t];
        if (t < cnt * 8) ws[t] = w1[(size_t)(start + base) * 8 + t];
        __syncthreads();
        for (int e = 0; e < cnt; e++) {
            float wv = ws[e * 8 + h];
            acc += wv * h1[(size_t)su[e] * 256 + t];
            wsum += wv;
        }
    }
    float o = acc / wsum + b1[t];
    x2[(size_t)v * 256 + t] = o > 0.f ? o : 0.f;
}

// ---------------- GEMM2 + layer-2 logits: [M,256]@[256,16] ----------------

__global__ __launch_bounds__(256) void k_gemm2(const float* __restrict__ X,
                                               const float* __restrict__ W,
                                               const float* __restrict__ asrc,
                                               const float* __restrict__ adst,
                                               float* __restrict__ h2,
                                               float* __restrict__ als,
                                               float* __restrict__ ald, int n) {
    __shared__ float xs[16][260];
    __shared__ float ws[256 * 16];
    int t = threadIdx.x;
    int r0 = blockIdx.x * 16;
#pragma unroll
    for (int i = 0; i < 16; i++) ws[t + i * 256] = W[t + i * 256];
#pragma unroll
    for (int i = 0; i < 16; i++) {
        int row = r0 + i;
        xs[i][t] = (row < n) ? X[(size_t)row * 256 + t] : 0.f;
    }
    __syncthreads();
    int nl = t >> 4, j = t & 15;
    float acc = 0.f;
    const float4* xv = (const float4*)&xs[nl][0];
#pragma unroll 8
    for (int k4 = 0; k4 < 64; k4++) {
        float4 a = xv[k4];
        int k = k4 * 4;
        acc += a.x * ws[k * 16 + j] + a.y * ws[(k + 1) * 16 + j] +
               a.z * ws[(k + 2) * 16 + j] + a.w * ws[(k + 3) * 16 + j];
    }
    int row = r0 + nl;
    float ps = acc * asrc[j], pd = acc * adst[j];
#pragma unroll
    for (int off = 8; off; off >>= 1) {
        ps += __shfl_down(ps, off, 16);
        pd += __shfl_down(pd, off, 16);
    }
    if (row < n) {
        h2[row * 16 + j] = acc;
        if (j == 0) {
            als[row] = ps;
            ald[row] = pd;
        }
    }
}

// ---------------- layer-2 aggregate + log_softmax (wave per node, 4/block) ----

__global__ __launch_bounds__(256) void k_agg2(const int* __restrict__ csr,
                                              const int* __restrict__ offs,
                                              const float* __restrict__ w2,
                                              const float* __restrict__ h2,
                                              const float* __restrict__ b2,
                                              float* __restrict__ out, int n) {
    int v = blockIdx.x * 4 + (threadIdx.x >> 6);
    if (v >= n) return;
    int lane = threadIdx.x & 63;
    int start = offs[v];
    int deg = offs[v + 1] - start;
    int c = lane & 15, q = lane >> 4;
    float acc = 0.f, wsum = 0.f;
    for (int e = q; e < deg; e += 4) {
        int p = start + e;
        float wv = w2[p];
        int u = csr[p];
        acc += wv * h2[(size_t)u * 16 + c];
        wsum += wv;
    }
    acc += __shfl_xor(acc, 32, 64);
    acc += __shfl_xor(acc, 16, 64);
    wsum += __shfl_xor(wsum, 32, 64);
    wsum += __shfl_xor(wsum, 16, 64);
    float o = acc / wsum + b2[c];
    float mx = o;
#pragma unroll
    for (int off = 8; off; off >>= 1) mx = fmaxf(mx, __shfl_xor(mx, off, 16));
    float s = __expf(o - mx);
#pragma unroll
    for (int off = 8; off; off >>= 1) s += __shfl_xor(s, off, 16);
    float res = o - mx - __logf(s);
    if (q == 0) out[(size_t)v * 16 + c] = res;
}

// ---------------- launch ----------------

extern "C" void kernel_launch(void* const* d_in, const int* in_sizes, int n_in,
                              void* d_out, int out_size, void* d_ws, size_t ws_size,
                              hipStream_t stream) {
    const float* x = (const float*)d_in[0];
    const int* ei = (const int*)d_in[1];
    const float* W1 = (const float*)d_in[2];
    const float* asrc1 = (const float*)d_in[3];
    const float* adst1 = (const float*)d_in[4];
    const float* b1 = (const float*)d_in[5];
    const float* W2 = (const float*)d_in[6];
    const float* asrc2 = (const float*)d_in[7];
    const float* adst2 = (const float*)d_in[8];
    const float* b2 = (const float*)d_in[9];
    float* out = (float*)d_out;

    int n = in_sizes[0] / 256;   // 50000
    int E = in_sizes[1] / 2;     // 800000
    int P = E + n;               // CSR slots incl. self loops
    const int* src = ei;
    const int* dst = ei + E;

    char* p = (char*)d_ws;
    auto alloc = [&](size_t bytes) {
        void* r = (void*)p;
        p += (bytes + 255) & ~(size_t)255;
        return r;
    };
    float* h1 = (float*)alloc((size_t)n * 256 * 4);
    float* x2 = (float*)alloc((size_t)n * 256 * 4);
    float* als1 = (float*)alloc((size_t)n * 8 * 4);
    float* ald1 = (float*)alloc((size_t)n * 8 * 4);
    float* h2 = (float*)alloc((size_t)n * 16 * 4);
    float* als2 = (float*)alloc((size_t)n * 4);
    float* ald2 = (float*)alloc((size_t)n * 4);
    int* deg = (int*)alloc((size_t)n * 4);
    int* offs = (int*)alloc((size_t)(n + 1) * 4);
    int* cursor = (int*)alloc((size_t)n * 4);
    int* csr = (int*)alloc((size_t)P * 4);
    int* dstv = (int*)alloc((size_t)P * 4);
    float* w1 = (float*)alloc((size_t)P * 8 * 4);
    float* w2 = (float*)alloc((size_t)P * 4);

    // CSR build
    k_init_deg<<<(n + 255) / 256, 256, 0, stream>>>(deg, n);
    k_hist<<<(E + 255) / 256, 256, 0, stream>>>(dst, deg, E);
    k_scan<<<1, 1024, 0, stream>>>(deg, offs, cursor, n);
    k_scatter<<<(P + 255) / 256, 256, 0, stream>>>(src, dst, cursor, csr, dstv, E, n);

    // layer 1
    k_gemm1<<<dim3((n + 63) / 64, 4), 256, 0, stream>>>(x, W1, h1, n);
    k_al1<<<n, 256, 0, stream>>>(h1, asrc1, adst1, als1, ald1);
    k_w1<<<(P * 8 + 255) / 256, 256, 0, stream>>>(csr, dstv, als1, ald1, w1, P);
    k_agg1<<<n, 256, 0, stream>>>(csr, offs, w1, h1, b1, x2);

    // layer 2
    k_gemm2<<<(n + 15) / 16, 256, 0, stream>>>(x2, W2, asrc2, adst2, h2, als2, ald2, n);
    k_w2<<<(P + 255) / 256, 256, 0, stream>>>(csr, dstv, als2, ald2, w2, P);
    k_agg2<<<(n + 3) / 4, 256, 0, stream>>>(csr, offs, w2, h2, b2, out, n);
}

// Round 5
// 487.909 us; speedup vs baseline: 1.5494x; 1.2532x over previous
//
#include <hip/hip_runtime.h>
#include <hip/hip_bf16.h>

// GATNet v4: v3b with k_agg1 OOB fix (128 threads/node, 2 bf16 cols per
// thread; v3b's 256-thread version wrote past each row and corrupted row v+1).

#define LRELU(x) ((x) > 0.f ? (x) : 0.2f * (x))

typedef __attribute__((ext_vector_type(8))) short short8;
typedef __attribute__((ext_vector_type(8))) unsigned short ushort8;
typedef __attribute__((ext_vector_type(4))) float f32x4;

__device__ inline unsigned short f2b(float f) {
    __hip_bfloat16 h = __float2bfloat16(f);
    return *reinterpret_cast<unsigned short*>(&h);
}
__device__ inline float b2f(unsigned short u) {
    __hip_bfloat16 h;
    *reinterpret_cast<unsigned short*>(&h) = u;
    return __bfloat162float(h);
}

// ---------------- CSR build ----------------

__global__ void k_init_deg(int* deg, int n) {
    int i = blockIdx.x * blockDim.x + threadIdx.x;
    if (i < n) deg[i] = 1;  // self loop
}

__global__ void k_hist(const int* __restrict__ dst, int* deg, int E) {
    int i = blockIdx.x * blockDim.x + threadIdx.x;
    if (i < E) atomicAdd(&deg[dst[i]], 1);
}

__global__ __launch_bounds__(1024) void k_scan(const int* __restrict__ deg,
                                               int* __restrict__ offs,
                                               int* __restrict__ cursor, int n) {
    __shared__ int sc[1024];
    int t = threadIdx.x;
    int CH = (n + 1023) / 1024;
    int s = t * CH;
    int e = min(s + CH, n);
    int sum = 0;
    for (int i = s; i < e; ++i) sum += deg[i];
    sc[t] = sum;
    __syncthreads();
    for (int off = 1; off < 1024; off <<= 1) {
        int v = 0;
        if (t >= off) v = sc[t - off];
        __syncthreads();
        sc[t] += v;
        __syncthreads();
    }
    int excl = sc[t] - sum;
    int run = excl;
    for (int i = s; i < e; ++i) {
        offs[i] = run;
        cursor[i] = run;
        run += deg[i];
    }
    if (t == 1023) offs[n] = sc[1023];
}

__global__ void k_scatter(const int* __restrict__ src, const int* __restrict__ dst,
                          int* cursor, int* __restrict__ csr, int* __restrict__ dstv,
                          int E, int n) {
    int i = blockIdx.x * blockDim.x + threadIdx.x;
    int s, d;
    if (i < E) {
        s = src[i];
        d = dst[i];
    } else if (i < E + n) {
        s = i - E;
        d = s;
    } else {
        return;
    }
    int p = atomicAdd(&cursor[d], 1);
    csr[p] = s;
    dstv[p] = d;
}

// ---------------- W1 pre-transpose + cast: W1t[n][k] bf16 ----------------

__global__ __launch_bounds__(256) void k_prepw(const float* __restrict__ W,
                                               unsigned short* __restrict__ Wt) {
    int k = blockIdx.x;   // 256
    int nn = threadIdx.x; // 256
    Wt[nn * 256 + k] = f2b(W[k * 256 + nn]);
}

// ---------------- GEMM1 (MFMA bf16): h1b[M,256] = bf16(A[M,256] @ W1) -------
// 128x128 block tile, 4 waves (2x2 of 64x64), 16x16x32 MFMA, K-chunks of 32.

__global__ __launch_bounds__(256) void k_gemm1(const float* __restrict__ A,
                                               const unsigned short* __restrict__ Wt,
                                               unsigned short* __restrict__ h1b, int M) {
    __shared__ unsigned short As[128][40];
    __shared__ unsigned short Bs[128][40];
    int t = threadIdx.x;
    int r0 = blockIdx.x * 128, c0 = blockIdx.y * 128;
    int srow = t >> 1, shalf = t & 1;  // staging: 128 rows x 2 halves of 16
    int lane = t & 63, w = t >> 6;
    int lane15 = lane & 15, quad = lane >> 4;
    int rbw = (w & 1) * 64, cbw = (w >> 1) * 64;

    f32x4 acc[4][4];
#pragma unroll
    for (int i = 0; i < 4; i++)
#pragma unroll
        for (int j = 0; j < 4; j++) acc[i][j] = (f32x4)0.f;

    for (int k0 = 0; k0 < 256; k0 += 32) {
        {
            int row = r0 + srow;
            ushort8 p0, p1;
            if (row < M) {
                const float4* sp = (const float4*)&A[(size_t)row * 256 + k0 + shalf * 16];
                float4 f0 = sp[0], f1 = sp[1], f2 = sp[2], f3 = sp[3];
                p0[0] = f2b(f0.x); p0[1] = f2b(f0.y); p0[2] = f2b(f0.z); p0[3] = f2b(f0.w);
                p0[4] = f2b(f1.x); p0[5] = f2b(f1.y); p0[6] = f2b(f1.z); p0[7] = f2b(f1.w);
                p1[0] = f2b(f2.x); p1[1] = f2b(f2.y); p1[2] = f2b(f2.z); p1[3] = f2b(f2.w);
                p1[4] = f2b(f3.x); p1[5] = f2b(f3.y); p1[6] = f2b(f3.z); p1[7] = f2b(f3.w);
            } else {
                p0 = (ushort8)0; p1 = (ushort8)0;
            }
            *(ushort8*)&As[srow][shalf * 16] = p0;
            *(ushort8*)&As[srow][shalf * 16 + 8] = p1;
            const ushort8* bp = (const ushort8*)&Wt[(size_t)(c0 + srow) * 256 + k0 + shalf * 16];
            *(ushort8*)&Bs[srow][shalf * 16] = bp[0];
            *(ushort8*)&Bs[srow][shalf * 16 + 8] = bp[1];
        }
        __syncthreads();
        short8 af[4], bf[4];
#pragma unroll
        for (int i = 0; i < 4; i++)
            af[i] = *(const short8*)&As[rbw + i * 16 + lane15][quad * 8];
#pragma unroll
        for (int j = 0; j < 4; j++)
            bf[j] = *(const short8*)&Bs[cbw + j * 16 + lane15][quad * 8];
#pragma unroll
        for (int i = 0; i < 4; i++)
#pragma unroll
            for (int j = 0; j < 4; j++)
                acc[i][j] = __builtin_amdgcn_mfma_f32_16x16x32_bf16(af[i], bf[j], acc[i][j], 0, 0, 0);
        __syncthreads();
    }
    // epilogue: C/D layout col=lane&15, row=quad*4+reg
#pragma unroll
    for (int i = 0; i < 4; i++) {
        int rowb = r0 + rbw + i * 16 + quad * 4;
#pragma unroll
        for (int j = 0; j < 4; j++) {
            int col = c0 + cbw + j * 16 + lane15;
#pragma unroll
            for (int r = 0; r < 4; r++) {
                int row = rowb + r;
                if (row < M) h1b[(size_t)row * 256 + col] = f2b(acc[i][j][r]);
            }
        }
    }
}

// ---------------- attention logits layer 1 (bf16 h1) ----------------

__global__ __launch_bounds__(256) void k_al1(const unsigned short* __restrict__ h1b,
                                             const float* __restrict__ asrc,
                                             const float* __restrict__ adst,
                                             float* __restrict__ als,
                                             float* __restrict__ ald) {
    int v = blockIdx.x, t = threadIdx.x;
    float hv = b2f(h1b[(size_t)v * 256 + t]);
    float ps = hv * asrc[t], pd = hv * adst[t];
#pragma unroll
    for (int off = 16; off; off >>= 1) {
        ps += __shfl_down(ps, off, 32);
        pd += __shfl_down(pd, off, 32);
    }
    if ((t & 31) == 0) {
        int h = t >> 5;
        als[v * 8 + h] = ps;
        ald[v * 8 + h] = pd;
    }
}

// ---------------- edge-parallel weight precompute ----------------

__global__ void k_w1(const int* __restrict__ csr, const int* __restrict__ dstv,
                     const float* __restrict__ als, const float* __restrict__ ald,
                     float* __restrict__ w, int P) {
    int i = blockIdx.x * blockDim.x + threadIdx.x;
    if (i >= P * 8) return;
    int p = i >> 3, h = i & 7;
    int u = csr[p], d = dstv[p];
    float x = als[u * 8 + h] + ald[d * 8 + h];
    w[i] = __expf(LRELU(x));
}

__global__ void k_w2(const int* __restrict__ csr, const int* __restrict__ dstv,
                     const float* __restrict__ als, const float* __restrict__ ald,
                     float* __restrict__ w, int P) {
    int p = blockIdx.x * blockDim.x + threadIdx.x;
    if (p >= P) return;
    float x = als[csr[p]] + ald[dstv[p]];
    w[p] = __expf(LRELU(x));
}

// ---------------- layer-1 aggregate: 128 thr/node, uint (2 bf16 cols) each --

__global__ __launch_bounds__(128) void k_agg1(const int* __restrict__ csr,
                                              const int* __restrict__ offs,
                                              const float* __restrict__ w1,
                                              const unsigned short* __restrict__ h1b,
                                              const float* __restrict__ b1,
                                              unsigned short* __restrict__ x2b) {
    int v = blockIdx.x;
    int t = threadIdx.x;           // t in [0,128): cols 2t, 2t+1; head = t>>4
    int start = offs[v];
    int deg = offs[v + 1] - start;
    __shared__ int su[32];
    __shared__ float ws[256];
    int h = t >> 4;
    float a0 = 0.f, a1 = 0.f, wsum = 0.f;
    for (int base = 0; base < deg; base += 32) {
        int cnt = min(32, deg - base);
        if (base) __syncthreads();
        if (t < cnt) su[t] = csr[start + base + t];
        for (int i = t; i < cnt * 8; i += 128) ws[i] = w1[(size_t)(start + base) * 8 + i];
        __syncthreads();
        for (int e = 0; e < cnt; e++) {
            float wv = ws[e * 8 + h];
            const unsigned int* hp = (const unsigned int*)(h1b + (size_t)su[e] * 256);
            unsigned int pk = hp[t];
            float f0 = b2f((unsigned short)(pk & 0xffffu));
            float f1 = b2f((unsigned short)(pk >> 16));
            a0 += wv * f0;
            a1 += wv * f1;
            wsum += wv;
        }
    }
    const float2* b1v = (const float2*)b1;
    float2 bb = b1v[t];
    float inv = 1.0f / wsum;
    float o0 = a0 * inv + bb.x;
    float o1 = a1 * inv + bb.y;
    o0 = o0 > 0.f ? o0 : 0.f;
    o1 = o1 > 0.f ? o1 : 0.f;
    unsigned int opk = (unsigned int)f2b(o0) | ((unsigned int)f2b(o1) << 16);
    ((unsigned int*)(x2b + (size_t)v * 256))[t] = opk;
}

// ---------------- GEMM2 + layer-2 logits: [M,256]@[256,16] (bf16 X) --------

__global__ __launch_bounds__(256) void k_gemm2(const unsigned short* __restrict__ Xb,
                                               const float* __restrict__ W,
                                               const float* __restrict__ asrc,
                                               const float* __restrict__ adst,
                                               float* __restrict__ h2,
                                               float* __restrict__ als,
                                               float* __restrict__ ald, int n) {
    __shared__ float xs[16][260];
    __shared__ float ws[256 * 16];
    int t = threadIdx.x;
    int r0 = blockIdx.x * 16;
#pragma unroll
    for (int i = 0; i < 16; i++) ws[t + i * 256] = W[t + i * 256];
#pragma unroll
    for (int i = 0; i < 16; i++) {
        int row = r0 + i;
        xs[i][t] = (row < n) ? b2f(Xb[(size_t)row * 256 + t]) : 0.f;
    }
    __syncthreads();
    int nl = t >> 4, j = t & 15;
    float acc = 0.f;
    const float4* xv = (const float4*)&xs[nl][0];
#pragma unroll 8
    for (int k4 = 0; k4 < 64; k4++) {
        float4 a = xv[k4];
        int k = k4 * 4;
        acc += a.x * ws[k * 16 + j] + a.y * ws[(k + 1) * 16 + j] +
               a.z * ws[(k + 2) * 16 + j] + a.w * ws[(k + 3) * 16 + j];
    }
    int row = r0 + nl;
    float ps = acc * asrc[j], pd = acc * adst[j];
#pragma unroll
    for (int off = 8; off; off >>= 1) {
        ps += __shfl_down(ps, off, 16);
        pd += __shfl_down(pd, off, 16);
    }
    if (row < n) {
        h2[row * 16 + j] = acc;
        if (j == 0) {
            als[row] = ps;
            ald[row] = pd;
        }
    }
}

// ---------------- layer-2 aggregate + log_softmax (wave per node, 4/block) ----

__global__ __launch_bounds__(256) void k_agg2(const int* __restrict__ csr,
                                              const int* __restrict__ offs,
                                              const float* __restrict__ w2,
                                              const float* __restrict__ h2,
                                              const float* __restrict__ b2,
                                              float* __restrict__ out, int n) {
    int v = blockIdx.x * 4 + (threadIdx.x >> 6);
    if (v >= n) return;
    int lane = threadIdx.x & 63;
    int start = offs[v];
    int deg = offs[v + 1] - start;
    int c = lane & 15, q = lane >> 4;
    float acc = 0.f, wsum = 0.f;
    for (int e = q; e < deg; e += 4) {
        int p = start + e;
        float wv = w2[p];
        int u = csr[p];
        acc += wv * h2[(size_t)u * 16 + c];
        wsum += wv;
    }
    acc += __shfl_xor(acc, 32, 64);
    acc += __shfl_xor(acc, 16, 64);
    wsum += __shfl_xor(wsum, 32, 64);
    wsum += __shfl_xor(wsum, 16, 64);
    float o = acc / wsum + b2[c];
    float mx = o;
#pragma unroll
    for (int off = 8; off; off >>= 1) mx = fmaxf(mx, __shfl_xor(mx, off, 16));
    float s = __expf(o - mx);
#pragma unroll
    for (int off = 8; off; off >>= 1) s += __shfl_xor(s, off, 16);
    float res = o - mx - __logf(s);
    if (q == 0) out[(size_t)v * 16 + c] = res;
}

// ---------------- launch ----------------

extern "C" void kernel_launch(void* const* d_in, const int* in_sizes, int n_in,
                              void* d_out, int out_size, void* d_ws, size_t ws_size,
                              hipStream_t stream) {
    const float* x = (const float*)d_in[0];
    const int* ei = (const int*)d_in[1];
    const float* W1 = (const float*)d_in[2];
    const float* asrc1 = (const float*)d_in[3];
    const float* adst1 = (const float*)d_in[4];
    const float* b1 = (const float*)d_in[5];
    const float* W2 = (const float*)d_in[6];
    const float* asrc2 = (const float*)d_in[7];
    const float* adst2 = (const float*)d_in[8];
    const float* b2 = (const float*)d_in[9];
    float* out = (float*)d_out;

    int n = in_sizes[0] / 256;   // 50000
    int E = in_sizes[1] / 2;     // 800000
    int P = E + n;
    const int* src = ei;
    const int* dst = ei + E;

    char* p = (char*)d_ws;
    auto alloc = [&](size_t bytes) {
        void* r = (void*)p;
        p += (bytes + 255) & ~(size_t)255;
        return r;
    };
    unsigned short* h1b = (unsigned short*)alloc((size_t)n * 256 * 2);
    unsigned short* x2b = (unsigned short*)alloc((size_t)n * 256 * 2);
    unsigned short* W1t = (unsigned short*)alloc((size_t)256 * 256 * 2);
    float* als1 = (float*)alloc((size_t)n * 8 * 4);
    float* ald1 = (float*)alloc((size_t)n * 8 * 4);
    float* h2 = (float*)alloc((size_t)n * 16 * 4);
    float* als2 = (float*)alloc((size_t)n * 4);
    float* ald2 = (float*)alloc((size_t)n * 4);
    int* deg = (int*)alloc((size_t)n * 4);
    int* offs = (int*)alloc((size_t)(n + 1) * 4);
    int* cursor = (int*)alloc((size_t)n * 4);
    int* csr = (int*)alloc((size_t)P * 4);
    int* dstv = (int*)alloc((size_t)P * 4);
    float* w1 = (float*)alloc((size_t)P * 8 * 4);
    float* w2 = (float*)alloc((size_t)P * 4);

    // CSR build
    k_init_deg<<<(n + 255) / 256, 256, 0, stream>>>(deg, n);
    k_hist<<<(E + 255) / 256, 256, 0, stream>>>(dst, deg, E);
    k_scan<<<1, 1024, 0, stream>>>(deg, offs, cursor, n);
    k_scatter<<<(P + 255) / 256, 256, 0, stream>>>(src, dst, cursor, csr, dstv, E, n);

    // layer 1
    k_prepw<<<256, 256, 0, stream>>>(W1, W1t);
    k_gemm1<<<dim3((n + 127) / 128, 2), 256, 0, stream>>>(x, W1t, h1b, n);
    k_al1<<<n, 256, 0, stream>>>(h1b, asrc1, adst1, als1, ald1);
    k_w1<<<(P * 8 + 255) / 256, 256, 0, stream>>>(csr, dstv, als1, ald1, w1, P);
    k_agg1<<<n, 128, 0, stream>>>(csr, offs, w1, h1b, b1, x2b);

    // layer 2
    k_gemm2<<<(n + 15) / 16, 256, 0, stream>>>(x2b, W2, asrc2, adst2, h2, als2, ald2, n);
    k_w2<<<(P + 255) / 256, 256, 0, stream>>>(csr, dstv, als2, ald2, w2, P);
    k_agg2<<<(n + 3) / 4, 256, 0, stream>>>(csr, offs, w2, h2, b2, out, n);
}

// Round 6
// 394.843 us; speedup vs baseline: 1.9146x; 1.2357x over previous
//
#include <hip/hip_runtime.h>
#include <hip/hip_bf16.h>

// GATNet v5: v4 + hierarchical 3-phase CSR scan (v4's single-block scan was
// 109 us, 22% of runtime, 0.14% occupancy — pure latency).

#define LRELU(x) ((x) > 0.f ? (x) : 0.2f * (x))

typedef __attribute__((ext_vector_type(8))) short short8;
typedef __attribute__((ext_vector_type(8))) unsigned short ushort8;
typedef __attribute__((ext_vector_type(4))) float f32x4;

__device__ inline unsigned short f2b(float f) {
    __hip_bfloat16 h = __float2bfloat16(f);
    return *reinterpret_cast<unsigned short*>(&h);
}
__device__ inline float b2f(unsigned short u) {
    __hip_bfloat16 h;
    *reinterpret_cast<unsigned short*>(&h) = u;
    return __bfloat162float(h);
}

// ---------------- CSR build ----------------

__global__ void k_init_deg(int* deg, int n) {
    int i = blockIdx.x * blockDim.x + threadIdx.x;
    if (i < n) deg[i] = 1;  // self loop
}

__global__ void k_hist(const int* __restrict__ dst, int* deg, int E) {
    int i = blockIdx.x * blockDim.x + threadIdx.x;
    if (i < E) atomicAdd(&deg[dst[i]], 1);
}

// 3-phase hierarchical exclusive scan of deg[n] -> offs/cursor

__global__ __launch_bounds__(256) void k_scanA(const int* __restrict__ deg,
                                               int* __restrict__ tmp,
                                               int* __restrict__ blocksum, int n) {
    __shared__ int sc[256];
    int b = blockIdx.x, t = threadIdx.x;
    int i = b * 256 + t;
    int v = (i < n) ? deg[i] : 0;
    sc[t] = v;
    __syncthreads();
    for (int off = 1; off < 256; off <<= 1) {
        int x = 0;
        if (t >= off) x = sc[t - off];
        __syncthreads();
        sc[t] += x;
        __syncthreads();
    }
    if (i < n) tmp[i] = sc[t] - v;
    if (t == 255) blocksum[b] = sc[255];
}

__global__ __launch_bounds__(256) void k_scanB(const int* __restrict__ blocksum,
                                               int* __restrict__ blockpre, int nb) {
    __shared__ int sc[256];
    int t = threadIdx.x;
    int v = (t < nb) ? blocksum[t] : 0;
    sc[t] = v;
    __syncthreads();
    for (int off = 1; off < 256; off <<= 1) {
        int x = 0;
        if (t >= off) x = sc[t - off];
        __syncthreads();
        sc[t] += x;
        __syncthreads();
    }
    if (t < nb) blockpre[t] = sc[t] - v;
}

__global__ __launch_bounds__(256) void k_scanC(const int* __restrict__ tmp,
                                               const int* __restrict__ blockpre,
                                               int* __restrict__ offs,
                                               int* __restrict__ cursor, int n, int P) {
    int b = blockIdx.x, t = threadIdx.x;
    int i = b * 256 + t;
    if (i < n) {
        int o = tmp[i] + blockpre[b];
        offs[i] = o;
        cursor[i] = o;
    }
    if (i == 0) offs[n] = P;
}

__global__ void k_scatter(const int* __restrict__ src, const int* __restrict__ dst,
                          int* cursor, int* __restrict__ csr, int* __restrict__ dstv,
                          int E, int n) {
    int i = blockIdx.x * blockDim.x + threadIdx.x;
    int s, d;
    if (i < E) {
        s = src[i];
        d = dst[i];
    } else if (i < E + n) {
        s = i - E;
        d = s;
    } else {
        return;
    }
    int p = atomicAdd(&cursor[d], 1);
    csr[p] = s;
    dstv[p] = d;
}

// ---------------- W1 pre-transpose + cast: W1t[n][k] bf16 ----------------

__global__ __launch_bounds__(256) void k_prepw(const float* __restrict__ W,
                                               unsigned short* __restrict__ Wt) {
    int k = blockIdx.x;   // 256
    int nn = threadIdx.x; // 256
    Wt[nn * 256 + k] = f2b(W[k * 256 + nn]);
}

// ---------------- GEMM1 (MFMA bf16): h1b[M,256] = bf16(A[M,256] @ W1) -------

__global__ __launch_bounds__(256) void k_gemm1(const float* __restrict__ A,
                                               const unsigned short* __restrict__ Wt,
                                               unsigned short* __restrict__ h1b, int M) {
    __shared__ unsigned short As[128][40];
    __shared__ unsigned short Bs[128][40];
    int t = threadIdx.x;
    int r0 = blockIdx.x * 128, c0 = blockIdx.y * 128;
    int srow = t >> 1, shalf = t & 1;
    int lane = t & 63, w = t >> 6;
    int lane15 = lane & 15, quad = lane >> 4;
    int rbw = (w & 1) * 64, cbw = (w >> 1) * 64;

    f32x4 acc[4][4];
#pragma unroll
    for (int i = 0; i < 4; i++)
#pragma unroll
        for (int j = 0; j < 4; j++) acc[i][j] = (f32x4)0.f;

    for (int k0 = 0; k0 < 256; k0 += 32) {
        {
            int row = r0 + srow;
            ushort8 p0, p1;
            if (row < M) {
                const float4* sp = (const float4*)&A[(size_t)row * 256 + k0 + shalf * 16];
                float4 f0 = sp[0], f1 = sp[1], f2 = sp[2], f3 = sp[3];
                p0[0] = f2b(f0.x); p0[1] = f2b(f0.y); p0[2] = f2b(f0.z); p0[3] = f2b(f0.w);
                p0[4] = f2b(f1.x); p0[5] = f2b(f1.y); p0[6] = f2b(f1.z); p0[7] = f2b(f1.w);
                p1[0] = f2b(f2.x); p1[1] = f2b(f2.y); p1[2] = f2b(f2.z); p1[3] = f2b(f2.w);
                p1[4] = f2b(f3.x); p1[5] = f2b(f3.y); p1[6] = f2b(f3.z); p1[7] = f2b(f3.w);
            } else {
                p0 = (ushort8)0; p1 = (ushort8)0;
            }
            *(ushort8*)&As[srow][shalf * 16] = p0;
            *(ushort8*)&As[srow][shalf * 16 + 8] = p1;
            const ushort8* bp = (const ushort8*)&Wt[(size_t)(c0 + srow) * 256 + k0 + shalf * 16];
            *(ushort8*)&Bs[srow][shalf * 16] = bp[0];
            *(ushort8*)&Bs[srow][shalf * 16 + 8] = bp[1];
        }
        __syncthreads();
        short8 af[4], bf[4];
#pragma unroll
        for (int i = 0; i < 4; i++)
            af[i] = *(const short8*)&As[rbw + i * 16 + lane15][quad * 8];
#pragma unroll
        for (int j = 0; j < 4; j++)
            bf[j] = *(const short8*)&Bs[cbw + j * 16 + lane15][quad * 8];
#pragma unroll
        for (int i = 0; i < 4; i++)
#pragma unroll
            for (int j = 0; j < 4; j++)
                acc[i][j] = __builtin_amdgcn_mfma_f32_16x16x32_bf16(af[i], bf[j], acc[i][j], 0, 0, 0);
        __syncthreads();
    }
#pragma unroll
    for (int i = 0; i < 4; i++) {
        int rowb = r0 + rbw + i * 16 + quad * 4;
#pragma unroll
        for (int j = 0; j < 4; j++) {
            int col = c0 + cbw + j * 16 + lane15;
#pragma unroll
            for (int r = 0; r < 4; r++) {
                int row = rowb + r;
                if (row < M) h1b[(size_t)row * 256 + col] = f2b(acc[i][j][r]);
            }
        }
    }
}

// ---------------- attention logits layer 1 (bf16 h1) ----------------

__global__ __launch_bounds__(256) void k_al1(const unsigned short* __restrict__ h1b,
                                             const float* __restrict__ asrc,
                                             const float* __restrict__ adst,
                                             float* __restrict__ als,
                                             float* __restrict__ ald) {
    int v = blockIdx.x, t = threadIdx.x;
    float hv = b2f(h1b[(size_t)v * 256 + t]);
    float ps = hv * asrc[t], pd = hv * adst[t];
#pragma unroll
    for (int off = 16; off; off >>= 1) {
        ps += __shfl_down(ps, off, 32);
        pd += __shfl_down(pd, off, 32);
    }
    if ((t & 31) == 0) {
        int h = t >> 5;
        als[v * 8 + h] = ps;
        ald[v * 8 + h] = pd;
    }
}

// ---------------- edge-parallel weight precompute ----------------

__global__ void k_w1(const int* __restrict__ csr, const int* __restrict__ dstv,
                     const float* __restrict__ als, const float* __restrict__ ald,
                     float* __restrict__ w, int P) {
    int i = blockIdx.x * blockDim.x + threadIdx.x;
    if (i >= P * 8) return;
    int p = i >> 3, h = i & 7;
    int u = csr[p], d = dstv[p];
    float x = als[u * 8 + h] + ald[d * 8 + h];
    w[i] = __expf(LRELU(x));
}

__global__ void k_w2(const int* __restrict__ csr, const int* __restrict__ dstv,
                     const float* __restrict__ als, const float* __restrict__ ald,
                     float* __restrict__ w, int P) {
    int p = blockIdx.x * blockDim.x + threadIdx.x;
    if (p >= P) return;
    float x = als[csr[p]] + ald[dstv[p]];
    w[p] = __expf(LRELU(x));
}

// ---------------- layer-1 aggregate: 128 thr/node, uint (2 bf16 cols) each --

__global__ __launch_bounds__(128) void k_agg1(const int* __restrict__ csr,
                                              const int* __restrict__ offs,
                                              const float* __restrict__ w1,
                                              const unsigned short* __restrict__ h1b,
                                              const float* __restrict__ b1,
                                              unsigned short* __restrict__ x2b) {
    int v = blockIdx.x;
    int t = threadIdx.x;           // t in [0,128): cols 2t, 2t+1; head = t>>4
    int start = offs[v];
    int deg = offs[v + 1] - start;
    __shared__ int su[32];
    __shared__ float ws[256];
    int h = t >> 4;
    float a0 = 0.f, a1 = 0.f, wsum = 0.f;
    for (int base = 0; base < deg; base += 32) {
        int cnt = min(32, deg - base);
        if (base) __syncthreads();
        if (t < cnt) su[t] = csr[start + base + t];
        for (int i = t; i < cnt * 8; i += 128) ws[i] = w1[(size_t)(start + base) * 8 + i];
        __syncthreads();
        for (int e = 0; e < cnt; e++) {
            float wv = ws[e * 8 + h];
            const unsigned int* hp = (const unsigned int*)(h1b + (size_t)su[e] * 256);
            unsigned int pk = hp[t];
            float f0 = b2f((unsigned short)(pk & 0xffffu));
            float f1 = b2f((unsigned short)(pk >> 16));
            a0 += wv * f0;
            a1 += wv * f1;
            wsum += wv;
        }
    }
    const float2* b1v = (const float2*)b1;
    float2 bb = b1v[t];
    float inv = 1.0f / wsum;
    float o0 = a0 * inv + bb.x;
    float o1 = a1 * inv + bb.y;
    o0 = o0 > 0.f ? o0 : 0.f;
    o1 = o1 > 0.f ? o1 : 0.f;
    unsigned int opk = (unsigned int)f2b(o0) | ((unsigned int)f2b(o1) << 16);
    ((unsigned int*)(x2b + (size_t)v * 256))[t] = opk;
}

// ---------------- GEMM2 + layer-2 logits: [M,256]@[256,16] (bf16 X) --------

__global__ __launch_bounds__(256) void k_gemm2(const unsigned short* __restrict__ Xb,
                                               const float* __restrict__ W,
                                               const float* __restrict__ asrc,
                                               const float* __restrict__ adst,
                                               float* __restrict__ h2,
                                               float* __restrict__ als,
                                               float* __restrict__ ald, int n) {
    __shared__ float xs[16][260];
    __shared__ float ws[256 * 16];
    int t = threadIdx.x;
    int r0 = blockIdx.x * 16;
#pragma unroll
    for (int i = 0; i < 16; i++) ws[t + i * 256] = W[t + i * 256];
#pragma unroll
    for (int i = 0; i < 16; i++) {
        int row = r0 + i;
        xs[i][t] = (row < n) ? b2f(Xb[(size_t)row * 256 + t]) : 0.f;
    }
    __syncthreads();
    int nl = t >> 4, j = t & 15;
    float acc = 0.f;
    const float4* xv = (const float4*)&xs[nl][0];
#pragma unroll 8
    for (int k4 = 0; k4 < 64; k4++) {
        float4 a = xv[k4];
        int k = k4 * 4;
        acc += a.x * ws[k * 16 + j] + a.y * ws[(k + 1) * 16 + j] +
               a.z * ws[(k + 2) * 16 + j] + a.w * ws[(k + 3) * 16 + j];
    }
    int row = r0 + nl;
    float ps = acc * asrc[j], pd = acc * adst[j];
#pragma unroll
    for (int off = 8; off; off >>= 1) {
        ps += __shfl_down(ps, off, 16);
        pd += __shfl_down(pd, off, 16);
    }
    if (row < n) {
        h2[row * 16 + j] = acc;
        if (j == 0) {
            als[row] = ps;
            ald[row] = pd;
        }
    }
}

// ---------------- layer-2 aggregate + log_softmax (wave per node, 4/block) ----

__global__ __launch_bounds__(256) void k_agg2(const int* __restrict__ csr,
                                              const int* __restrict__ offs,
                                              const float* __restrict__ w2,
                                              const float* __restrict__ h2,
                                              const float* __restrict__ b2,
                                              float* __restrict__ out, int n) {
    int v = blockIdx.x * 4 + (threadIdx.x >> 6);
    if (v >= n) return;
    int lane = threadIdx.x & 63;
    int start = offs[v];
    int deg = offs[v + 1] - start;
    int c = lane & 15, q = lane >> 4;
    float acc = 0.f, wsum = 0.f;
    for (int e = q; e < deg; e += 4) {
        int p = start + e;
        float wv = w2[p];
        int u = csr[p];
        acc += wv * h2[(size_t)u * 16 + c];
        wsum += wv;
    }
    acc += __shfl_xor(acc, 32, 64);
    acc += __shfl_xor(acc, 16, 64);
    wsum += __shfl_xor(wsum, 32, 64);
    wsum += __shfl_xor(wsum, 16, 64);
    float o = acc / wsum + b2[c];
    float mx = o;
#pragma unroll
    for (int off = 8; off; off >>= 1) mx = fmaxf(mx, __shfl_xor(mx, off, 16));
    float s = __expf(o - mx);
#pragma unroll
    for (int off = 8; off; off >>= 1) s += __shfl_xor(s, off, 16);
    float res = o - mx - __logf(s);
    if (q == 0) out[(size_t)v * 16 + c] = res;
}

// ---------------- launch ----------------

extern "C" void kernel_launch(void* const* d_in, const int* in_sizes, int n_in,
                              void* d_out, int out_size, void* d_ws, size_t ws_size,
                              hipStream_t stream) {
    const float* x = (const float*)d_in[0];
    const int* ei = (const int*)d_in[1];
    const float* W1 = (const float*)d_in[2];
    const float* asrc1 = (const float*)d_in[3];
    const float* adst1 = (const float*)d_in[4];
    const float* b1 = (const float*)d_in[5];
    const float* W2 = (const float*)d_in[6];
    const float* asrc2 = (const float*)d_in[7];
    const float* adst2 = (const float*)d_in[8];
    const float* b2 = (const float*)d_in[9];
    float* out = (float*)d_out;

    int n = in_sizes[0] / 256;   // 50000
    int E = in_sizes[1] / 2;     // 800000
    int P = E + n;
    const int* src = ei;
    const int* dst = ei + E;
    int NB = (n + 255) / 256;    // 196 scan blocks

    char* p = (char*)d_ws;
    auto alloc = [&](size_t bytes) {
        void* r = (void*)p;
        p += (bytes + 255) & ~(size_t)255;
        return r;
    };
    unsigned short* h1b = (unsigned short*)alloc((size_t)n * 256 * 2);
    unsigned short* x2b = (unsigned short*)alloc((size_t)n * 256 * 2);
    unsigned short* W1t = (unsigned short*)alloc((size_t)256 * 256 * 2);
    float* als1 = (float*)alloc((size_t)n * 8 * 4);
    float* ald1 = (float*)alloc((size_t)n * 8 * 4);
    float* h2 = (float*)alloc((size_t)n * 16 * 4);
    float* als2 = (float*)alloc((size_t)n * 4);
    float* ald2 = (float*)alloc((size_t)n * 4);
    int* deg = (int*)alloc((size_t)n * 4);
    int* offs = (int*)alloc((size_t)(n + 1) * 4);
    int* cursor = (int*)alloc((size_t)n * 4);
    int* stmp = (int*)alloc((size_t)n * 4);
    int* blocksum = (int*)alloc((size_t)NB * 4);
    int* blockpre = (int*)alloc((size_t)NB * 4);
    int* csr = (int*)alloc((size_t)P * 4);
    int* dstv = (int*)alloc((size_t)P * 4);
    float* w1 = (float*)alloc((size_t)P * 8 * 4);
    float* w2 = (float*)alloc((size_t)P * 4);

    // CSR build
    k_init_deg<<<(n + 255) / 256, 256, 0, stream>>>(deg, n);
    k_hist<<<(E + 255) / 256, 256, 0, stream>>>(dst, deg, E);
    k_scanA<<<NB, 256, 0, stream>>>(deg, stmp, blocksum, n);
    k_scanB<<<1, 256, 0, stream>>>(blocksum, blockpre, NB);
    k_scanC<<<NB, 256, 0, stream>>>(stmp, blockpre, offs, cursor, n, P);
    k_scatter<<<(P + 255) / 256, 256, 0, stream>>>(src, dst, cursor, csr, dstv, E, n);

    // layer 1
    k_prepw<<<256, 256, 0, stream>>>(W1, W1t);
    k_gemm1<<<dim3((n + 127) / 128, 2), 256, 0, stream>>>(x, W1t, h1b, n);
    k_al1<<<n, 256, 0, stream>>>(h1b, asrc1, adst1, als1, ald1);
    k_w1<<<(P * 8 + 255) / 256, 256, 0, stream>>>(csr, dstv, als1, ald1, w1, P);
    k_agg1<<<n, 128, 0, stream>>>(csr, offs, w1, h1b, b1, x2b);

    // layer 2
    k_gemm2<<<(n + 15) / 16, 256, 0, stream>>>(x2b, W2, asrc2, adst2, h2, als2, ald2, n);
    k_w2<<<(P + 255) / 256, 256, 0, stream>>>(csr, dstv, als2, ald2, w2, P);
    k_agg2<<<(n + 3) / 4, 256, 0, stream>>>(csr, offs, w2, h2, b2, out, n);
}

// Round 7
// 368.263 us; speedup vs baseline: 2.0528x; 1.0722x over previous
//
#include <hip/hip_runtime.h>
#include <hip/hip_bf16.h>

// GATNet v6: fuse attention-weight computation into aggregators (k_w1/k_w2 and
// dstv/w1/w2 buffers deleted), wave-per-node k_al1 with uint2 bf16 loads.

#define LRELU(x) ((x) > 0.f ? (x) : 0.2f * (x))

typedef __attribute__((ext_vector_type(8))) short short8;
typedef __attribute__((ext_vector_type(8))) unsigned short ushort8;
typedef __attribute__((ext_vector_type(4))) float f32x4;

__device__ inline unsigned short f2b(float f) {
    __hip_bfloat16 h = __float2bfloat16(f);
    return *reinterpret_cast<unsigned short*>(&h);
}
__device__ inline float b2f(unsigned short u) {
    __hip_bfloat16 h;
    *reinterpret_cast<unsigned short*>(&h) = u;
    return __bfloat162float(h);
}

// ---------------- CSR build ----------------

__global__ void k_init_deg(int* deg, int n) {
    int i = blockIdx.x * blockDim.x + threadIdx.x;
    if (i < n) deg[i] = 1;  // self loop
}

__global__ void k_hist(const int* __restrict__ dst, int* deg, int E) {
    int i = blockIdx.x * blockDim.x + threadIdx.x;
    if (i < E) atomicAdd(&deg[dst[i]], 1);
}

__global__ __launch_bounds__(256) void k_scanA(const int* __restrict__ deg,
                                               int* __restrict__ tmp,
                                               int* __restrict__ blocksum, int n) {
    __shared__ int sc[256];
    int b = blockIdx.x, t = threadIdx.x;
    int i = b * 256 + t;
    int v = (i < n) ? deg[i] : 0;
    sc[t] = v;
    __syncthreads();
    for (int off = 1; off < 256; off <<= 1) {
        int x = 0;
        if (t >= off) x = sc[t - off];
        __syncthreads();
        sc[t] += x;
        __syncthreads();
    }
    if (i < n) tmp[i] = sc[t] - v;
    if (t == 255) blocksum[b] = sc[255];
}

__global__ __launch_bounds__(256) void k_scanB(const int* __restrict__ blocksum,
                                               int* __restrict__ blockpre, int nb) {
    __shared__ int sc[256];
    int t = threadIdx.x;
    int v = (t < nb) ? blocksum[t] : 0;
    sc[t] = v;
    __syncthreads();
    for (int off = 1; off < 256; off <<= 1) {
        int x = 0;
        if (t >= off) x = sc[t - off];
        __syncthreads();
        sc[t] += x;
        __syncthreads();
    }
    if (t < nb) blockpre[t] = sc[t] - v;
}

__global__ __launch_bounds__(256) void k_scanC(const int* __restrict__ tmp,
                                               const int* __restrict__ blockpre,
                                               int* __restrict__ offs,
                                               int* __restrict__ cursor, int n, int P) {
    int b = blockIdx.x, t = threadIdx.x;
    int i = b * 256 + t;
    if (i < n) {
        int o = tmp[i] + blockpre[b];
        offs[i] = o;
        cursor[i] = o;
    }
    if (i == 0) offs[n] = P;
}

__global__ void k_scatter(const int* __restrict__ src, const int* __restrict__ dst,
                          int* cursor, int* __restrict__ csr, int E, int n) {
    int i = blockIdx.x * blockDim.x + threadIdx.x;
    int s, d;
    if (i < E) {
        s = src[i];
        d = dst[i];
    } else if (i < E + n) {
        s = i - E;
        d = s;
    } else {
        return;
    }
    int p = atomicAdd(&cursor[d], 1);
    csr[p] = s;
}

// ---------------- W1 pre-transpose + cast: W1t[n][k] bf16 ----------------

__global__ __launch_bounds__(256) void k_prepw(const float* __restrict__ W,
                                               unsigned short* __restrict__ Wt) {
    int k = blockIdx.x;   // 256
    int nn = threadIdx.x; // 256
    Wt[nn * 256 + k] = f2b(W[k * 256 + nn]);
}

// ---------------- GEMM1 (MFMA bf16): h1b[M,256] = bf16(A[M,256] @ W1) -------

__global__ __launch_bounds__(256) void k_gemm1(const float* __restrict__ A,
                                               const unsigned short* __restrict__ Wt,
                                               unsigned short* __restrict__ h1b, int M) {
    __shared__ unsigned short As[128][40];
    __shared__ unsigned short Bs[128][40];
    int t = threadIdx.x;
    int r0 = blockIdx.x * 128, c0 = blockIdx.y * 128;
    int srow = t >> 1, shalf = t & 1;
    int lane = t & 63, w = t >> 6;
    int lane15 = lane & 15, quad = lane >> 4;
    int rbw = (w & 1) * 64, cbw = (w >> 1) * 64;

    f32x4 acc[4][4];
#pragma unroll
    for (int i = 0; i < 4; i++)
#pragma unroll
        for (int j = 0; j < 4; j++) acc[i][j] = (f32x4)0.f;

    for (int k0 = 0; k0 < 256; k0 += 32) {
        {
            int row = r0 + srow;
            ushort8 p0, p1;
            if (row < M) {
                const float4* sp = (const float4*)&A[(size_t)row * 256 + k0 + shalf * 16];
                float4 f0 = sp[0], f1 = sp[1], f2 = sp[2], f3 = sp[3];
                p0[0] = f2b(f0.x); p0[1] = f2b(f0.y); p0[2] = f2b(f0.z); p0[3] = f2b(f0.w);
                p0[4] = f2b(f1.x); p0[5] = f2b(f1.y); p0[6] = f2b(f1.z); p0[7] = f2b(f1.w);
                p1[0] = f2b(f2.x); p1[1] = f2b(f2.y); p1[2] = f2b(f2.z); p1[3] = f2b(f2.w);
                p1[4] = f2b(f3.x); p1[5] = f2b(f3.y); p1[6] = f2b(f3.z); p1[7] = f2b(f3.w);
            } else {
                p0 = (ushort8)0; p1 = (ushort8)0;
            }
            *(ushort8*)&As[srow][shalf * 16] = p0;
            *(ushort8*)&As[srow][shalf * 16 + 8] = p1;
            const ushort8* bp = (const ushort8*)&Wt[(size_t)(c0 + srow) * 256 + k0 + shalf * 16];
            *(ushort8*)&Bs[srow][shalf * 16] = bp[0];
            *(ushort8*)&Bs[srow][shalf * 16 + 8] = bp[1];
        }
        __syncthreads();
        short8 af[4], bf[4];
#pragma unroll
        for (int i = 0; i < 4; i++)
            af[i] = *(const short8*)&As[rbw + i * 16 + lane15][quad * 8];
#pragma unroll
        for (int j = 0; j < 4; j++)
            bf[j] = *(const short8*)&Bs[cbw + j * 16 + lane15][quad * 8];
#pragma unroll
        for (int i = 0; i < 4; i++)
#pragma unroll
            for (int j = 0; j < 4; j++)
                acc[i][j] = __builtin_amdgcn_mfma_f32_16x16x32_bf16(af[i], bf[j], acc[i][j], 0, 0, 0);
        __syncthreads();
    }
#pragma unroll
    for (int i = 0; i < 4; i++) {
        int rowb = r0 + rbw + i * 16 + quad * 4;
#pragma unroll
        for (int j = 0; j < 4; j++) {
            int col = c0 + cbw + j * 16 + lane15;
#pragma unroll
            for (int r = 0; r < 4; r++) {
                int row = rowb + r;
                if (row < M) h1b[(size_t)row * 256 + col] = f2b(acc[i][j][r]);
            }
        }
    }
}

// ---------------- attention logits layer 1: wave per node, 4 nodes/block ----

__global__ __launch_bounds__(256) void k_al1(const unsigned short* __restrict__ h1b,
                                             const float* __restrict__ asrc,
                                             const float* __restrict__ adst,
                                             float* __restrict__ als,
                                             float* __restrict__ ald, int n) {
    int v = blockIdx.x * 4 + (threadIdx.x >> 6);
    if (v >= n) return;
    int lane = threadIdx.x & 63;      // cols lane*4..+3, head = lane>>3
    const uint2* hp = (const uint2*)(h1b + (size_t)v * 256);
    uint2 pk = hp[lane];
    float f0 = __uint_as_float(pk.x << 16);
    float f1 = __uint_as_float(pk.x & 0xffff0000u);
    float f2 = __uint_as_float(pk.y << 16);
    float f3 = __uint_as_float(pk.y & 0xffff0000u);
    float4 a_s = ((const float4*)asrc)[lane];
    float4 a_d = ((const float4*)adst)[lane];
    float ps = f0 * a_s.x + f1 * a_s.y + f2 * a_s.z + f3 * a_s.w;
    float pd = f0 * a_d.x + f1 * a_d.y + f2 * a_d.z + f3 * a_d.w;
#pragma unroll
    for (int off = 1; off < 8; off <<= 1) {
        ps += __shfl_xor(ps, off, 64);
        pd += __shfl_xor(pd, off, 64);
    }
    if ((lane & 7) == 0) {
        int h = lane >> 3;
        als[v * 8 + h] = ps;
        ald[v * 8 + h] = pd;
    }
}

// ---------------- layer-1 aggregate: fused weights, 128 thr/node ------------

__global__ __launch_bounds__(128) void k_agg1(const int* __restrict__ csr,
                                              const int* __restrict__ offs,
                                              const float* __restrict__ als,
                                              const float* __restrict__ aldg,
                                              const unsigned short* __restrict__ h1b,
                                              const float* __restrict__ b1,
                                              unsigned short* __restrict__ x2b) {
    int v = blockIdx.x;
    int t = threadIdx.x;           // t in [0,128): cols 2t,2t+1; head = t>>4
    int start = offs[v];
    int deg = offs[v + 1] - start;
    __shared__ float aldv[8];
    __shared__ int su[32];
    __shared__ float ws[256];
    if (t < 8) aldv[t] = aldg[v * 8 + t];
    __syncthreads();
    int h = t >> 4;
    float a0 = 0.f, a1 = 0.f, wsum = 0.f;
    for (int base = 0; base < deg; base += 32) {
        int cnt = min(32, deg - base);
        if (base) __syncthreads();
        if (t < cnt) {
            int u = csr[start + base + t];
            su[t] = u;
            const float4* ap = (const float4*)(als + (size_t)u * 8);
            float4 x0 = ap[0], x1 = ap[1];
            float e0 = x0.x + aldv[0], e1 = x0.y + aldv[1];
            float e2 = x0.z + aldv[2], e3 = x0.w + aldv[3];
            float e4 = x1.x + aldv[4], e5 = x1.y + aldv[5];
            float e6 = x1.z + aldv[6], e7 = x1.w + aldv[7];
            ws[t * 8 + 0] = __expf(LRELU(e0));
            ws[t * 8 + 1] = __expf(LRELU(e1));
            ws[t * 8 + 2] = __expf(LRELU(e2));
            ws[t * 8 + 3] = __expf(LRELU(e3));
            ws[t * 8 + 4] = __expf(LRELU(e4));
            ws[t * 8 + 5] = __expf(LRELU(e5));
            ws[t * 8 + 6] = __expf(LRELU(e6));
            ws[t * 8 + 7] = __expf(LRELU(e7));
        }
        __syncthreads();
        for (int e = 0; e < cnt; e++) {
            float wv = ws[e * 8 + h];
            const unsigned int* hp = (const unsigned int*)(h1b + (size_t)su[e] * 256);
            unsigned int pk = hp[t];
            float f0 = __uint_as_float(pk << 16);
            float f1 = __uint_as_float(pk & 0xffff0000u);
            a0 += wv * f0;
            a1 += wv * f1;
            wsum += wv;
        }
    }
    const float2* b1v = (const float2*)b1;
    float2 bb = b1v[t];
    float inv = 1.0f / wsum;
    float o0 = a0 * inv + bb.x;
    float o1 = a1 * inv + bb.y;
    o0 = o0 > 0.f ? o0 : 0.f;
    o1 = o1 > 0.f ? o1 : 0.f;
    unsigned int opk = (unsigned int)f2b(o0) | ((unsigned int)f2b(o1) << 16);
    ((unsigned int*)(x2b + (size_t)v * 256))[t] = opk;
}

// ---------------- GEMM2 + layer-2 logits: [M,256]@[256,16] (bf16 X) --------

__global__ __launch_bounds__(256) void k_gemm2(const unsigned short* __restrict__ Xb,
                                               const float* __restrict__ W,
                                               const float* __restrict__ asrc,
                                               const float* __restrict__ adst,
                                               float* __restrict__ h2,
                                               float* __restrict__ als,
                                               float* __restrict__ ald, int n) {
    __shared__ float xs[16][260];
    __shared__ float ws[256 * 16];
    int t = threadIdx.x;
    int r0 = blockIdx.x * 16;
#pragma unroll
    for (int i = 0; i < 16; i++) ws[t + i * 256] = W[t + i * 256];
#pragma unroll
    for (int i = 0; i < 16; i++) {
        int row = r0 + i;
        xs[i][t] = (row < n) ? b2f(Xb[(size_t)row * 256 + t]) : 0.f;
    }
    __syncthreads();
    int nl = t >> 4, j = t & 15;
    float acc = 0.f;
    const float4* xv = (const float4*)&xs[nl][0];
#pragma unroll 8
    for (int k4 = 0; k4 < 64; k4++) {
        float4 a = xv[k4];
        int k = k4 * 4;
        acc += a.x * ws[k * 16 + j] + a.y * ws[(k + 1) * 16 + j] +
               a.z * ws[(k + 2) * 16 + j] + a.w * ws[(k + 3) * 16 + j];
    }
    int row = r0 + nl;
    float ps = acc * asrc[j], pd = acc * adst[j];
#pragma unroll
    for (int off = 8; off; off >>= 1) {
        ps += __shfl_down(ps, off, 16);
        pd += __shfl_down(pd, off, 16);
    }
    if (row < n) {
        h2[row * 16 + j] = acc;
        if (j == 0) {
            als[row] = ps;
            ald[row] = pd;
        }
    }
}

// ---------------- layer-2 aggregate (fused w) + log_softmax -----------------

__global__ __launch_bounds__(256) void k_agg2(const int* __restrict__ csr,
                                              const int* __restrict__ offs,
                                              const float* __restrict__ als,
                                              const float* __restrict__ aldg,
                                              const float* __restrict__ h2,
                                              const float* __restrict__ b2,
                                              float* __restrict__ out, int n) {
    int v = blockIdx.x * 4 + (threadIdx.x >> 6);
    if (v >= n) return;
    int lane = threadIdx.x & 63;
    int start = offs[v];
    int deg = offs[v + 1] - start;
    float aldv = aldg[v];
    int c = lane & 15, q = lane >> 4;
    float acc = 0.f, wsum = 0.f;
    for (int e = q; e < deg; e += 4) {
        int u = csr[start + e];
        float x = als[u] + aldv;
        float wv = __expf(LRELU(x));
        acc += wv * h2[(size_t)u * 16 + c];
        wsum += wv;
    }
    acc += __shfl_xor(acc, 32, 64);
    acc += __shfl_xor(acc, 16, 64);
    wsum += __shfl_xor(wsum, 32, 64);
    wsum += __shfl_xor(wsum, 16, 64);
    float o = acc / wsum + b2[c];
    float mx = o;
#pragma unroll
    for (int off = 8; off; off >>= 1) mx = fmaxf(mx, __shfl_xor(mx, off, 16));
    float s = __expf(o - mx);
#pragma unroll
    for (int off = 8; off; off >>= 1) s += __shfl_xor(s, off, 16);
    float res = o - mx - __logf(s);
    if (q == 0) out[(size_t)v * 16 + c] = res;
}

// ---------------- launch ----------------

extern "C" void kernel_launch(void* const* d_in, const int* in_sizes, int n_in,
                              void* d_out, int out_size, void* d_ws, size_t ws_size,
                              hipStream_t stream) {
    const float* x = (const float*)d_in[0];
    const int* ei = (const int*)d_in[1];
    const float* W1 = (const float*)d_in[2];
    const float* asrc1 = (const float*)d_in[3];
    const float* adst1 = (const float*)d_in[4];
    const float* b1 = (const float*)d_in[5];
    const float* W2 = (const float*)d_in[6];
    const float* asrc2 = (const float*)d_in[7];
    const float* adst2 = (const float*)d_in[8];
    const float* b2 = (const float*)d_in[9];
    float* out = (float*)d_out;

    int n = in_sizes[0] / 256;   // 50000
    int E = in_sizes[1] / 2;     // 800000
    int P = E + n;
    const int* src = ei;
    const int* dst = ei + E;
    int NB = (n + 255) / 256;

    char* p = (char*)d_ws;
    auto alloc = [&](size_t bytes) {
        void* r = (void*)p;
        p += (bytes + 255) & ~(size_t)255;
        return r;
    };
    unsigned short* h1b = (unsigned short*)alloc((size_t)n * 256 * 2);
    unsigned short* x2b = (unsigned short*)alloc((size_t)n * 256 * 2);
    unsigned short* W1t = (unsigned short*)alloc((size_t)256 * 256 * 2);
    float* als1 = (float*)alloc((size_t)n * 8 * 4);
    float* ald1 = (float*)alloc((size_t)n * 8 * 4);
    float* h2 = (float*)alloc((size_t)n * 16 * 4);
    float* als2 = (float*)alloc((size_t)n * 4);
    float* ald2 = (float*)alloc((size_t)n * 4);
    int* deg = (int*)alloc((size_t)n * 4);
    int* offs = (int*)alloc((size_t)(n + 1) * 4);
    int* cursor = (int*)alloc((size_t)n * 4);
    int* stmp = (int*)alloc((size_t)n * 4);
    int* blocksum = (int*)alloc((size_t)NB * 4);
    int* blockpre = (int*)alloc((size_t)NB * 4);
    int* csr = (int*)alloc((size_t)P * 4);

    // CSR build
    k_init_deg<<<(n + 255) / 256, 256, 0, stream>>>(deg, n);
    k_hist<<<(E + 255) / 256, 256, 0, stream>>>(dst, deg, E);
    k_scanA<<<NB, 256, 0, stream>>>(deg, stmp, blocksum, n);
    k_scanB<<<1, 256, 0, stream>>>(blocksum, blockpre, NB);
    k_scanC<<<NB, 256, 0, stream>>>(stmp, blockpre, offs, cursor, n, P);
    k_scatter<<<(P + 255) / 256, 256, 0, stream>>>(src, dst, cursor, csr, E, n);

    // layer 1
    k_prepw<<<256, 256, 0, stream>>>(W1, W1t);
    k_gemm1<<<dim3((n + 127) / 128, 2), 256, 0, stream>>>(x, W1t, h1b, n);
    k_al1<<<(n + 3) / 4, 256, 0, stream>>>(h1b, asrc1, adst1, als1, ald1, n);
    k_agg1<<<n, 128, 0, stream>>>(csr, offs, als1, ald1, h1b, b1, x2b);

    // layer 2
    k_gemm2<<<(n + 15) / 16, 256, 0, stream>>>(x2b, W2, asrc2, adst2, h2, als2, ald2, n);
    k_agg2<<<(n + 3) / 4, 256, 0, stream>>>(csr, offs, als2, ald2, h2, b2, out, n);
}

// Round 8
// 343.915 us; speedup vs baseline: 2.1982x; 1.0708x over previous
//
#include <hip/hip_runtime.h>
#include <hip/hip_bf16.h>

// GATNet v7: agg1 ws stride-33 (kills 8-way bank conflict), MFMA gemm2 with
// fused layer-2 logits + bf16 h2, k_init_deg replaced by hipMemsetAsync.

#define LRELU(x) ((x) > 0.f ? (x) : 0.2f * (x))

typedef __attribute__((ext_vector_type(8))) short short8;
typedef __attribute__((ext_vector_type(8))) unsigned short ushort8;
typedef __attribute__((ext_vector_type(4))) float f32x4;

__device__ inline unsigned short f2b(float f) {
    __hip_bfloat16 h = __float2bfloat16(f);
    return *reinterpret_cast<unsigned short*>(&h);
}
__device__ inline float b2f(unsigned short u) {
    __hip_bfloat16 h;
    *reinterpret_cast<unsigned short*>(&h) = u;
    return __bfloat162float(h);
}

// ---------------- CSR build ----------------

__global__ void k_hist(const int* __restrict__ dst, int* deg, int E) {
    int i = blockIdx.x * blockDim.x + threadIdx.x;
    if (i < E) atomicAdd(&deg[dst[i]], 1);
}

// deg[i]+1 (self loop) scanned hierarchically

__global__ __launch_bounds__(256) void k_scanA(const int* __restrict__ deg,
                                               int* __restrict__ tmp,
                                               int* __restrict__ blocksum, int n) {
    __shared__ int sc[256];
    int b = blockIdx.x, t = threadIdx.x;
    int i = b * 256 + t;
    int v = (i < n) ? deg[i] + 1 : 0;
    sc[t] = v;
    __syncthreads();
    for (int off = 1; off < 256; off <<= 1) {
        int x = 0;
        if (t >= off) x = sc[t - off];
        __syncthreads();
        sc[t] += x;
        __syncthreads();
    }
    if (i < n) tmp[i] = sc[t] - v;
    if (t == 255) blocksum[b] = sc[255];
}

__global__ __launch_bounds__(256) void k_scanB(const int* __restrict__ blocksum,
                                               int* __restrict__ blockpre, int nb) {
    __shared__ int sc[256];
    int t = threadIdx.x;
    int v = (t < nb) ? blocksum[t] : 0;
    sc[t] = v;
    __syncthreads();
    for (int off = 1; off < 256; off <<= 1) {
        int x = 0;
        if (t >= off) x = sc[t - off];
        __syncthreads();
        sc[t] += x;
        __syncthreads();
    }
    if (t < nb) blockpre[t] = sc[t] - v;
}

__global__ __launch_bounds__(256) void k_scanC(const int* __restrict__ tmp,
                                               const int* __restrict__ blockpre,
                                               int* __restrict__ offs,
                                               int* __restrict__ cursor, int n, int P) {
    int b = blockIdx.x, t = threadIdx.x;
    int i = b * 256 + t;
    if (i < n) {
        int o = tmp[i] + blockpre[b];
        offs[i] = o;
        cursor[i] = o;
    }
    if (i == 0) offs[n] = P;
}

__global__ void k_scatter(const int* __restrict__ src, const int* __restrict__ dst,
                          int* cursor, int* __restrict__ csr, int E, int n) {
    int i = blockIdx.x * blockDim.x + threadIdx.x;
    int s, d;
    if (i < E) {
        s = src[i];
        d = dst[i];
    } else if (i < E + n) {
        s = i - E;
        d = s;
    } else {
        return;
    }
    int p = atomicAdd(&cursor[d], 1);
    csr[p] = s;
}

// ---------------- weight prep: W1t[256][256], W2t[16][256] bf16 -------------

__global__ __launch_bounds__(256) void k_prepw(const float* __restrict__ W,
                                               unsigned short* __restrict__ Wt) {
    int k = blockIdx.x;   // 256
    int nn = threadIdx.x; // 256
    Wt[nn * 256 + k] = f2b(W[k * 256 + nn]);
}

__global__ __launch_bounds__(256) void k_prepw2(const float* __restrict__ W,
                                                unsigned short* __restrict__ Wt) {
    int nn = blockIdx.x;  // 16
    int k = threadIdx.x;  // 256
    Wt[nn * 256 + k] = f2b(W[k * 16 + nn]);
}

// ---------------- GEMM1 (MFMA bf16): h1b[M,256] = bf16(A[M,256] @ W1) -------

__global__ __launch_bounds__(256) void k_gemm1(const float* __restrict__ A,
                                               const unsigned short* __restrict__ Wt,
                                               unsigned short* __restrict__ h1b, int M) {
    __shared__ unsigned short As[128][40];
    __shared__ unsigned short Bs[128][40];
    int t = threadIdx.x;
    int r0 = blockIdx.x * 128, c0 = blockIdx.y * 128;
    int srow = t >> 1, shalf = t & 1;
    int lane = t & 63, w = t >> 6;
    int lane15 = lane & 15, quad = lane >> 4;
    int rbw = (w & 1) * 64, cbw = (w >> 1) * 64;

    f32x4 acc[4][4];
#pragma unroll
    for (int i = 0; i < 4; i++)
#pragma unroll
        for (int j = 0; j < 4; j++) acc[i][j] = (f32x4)0.f;

    for (int k0 = 0; k0 < 256; k0 += 32) {
        {
            int row = r0 + srow;
            ushort8 p0, p1;
            if (row < M) {
                const float4* sp = (const float4*)&A[(size_t)row * 256 + k0 + shalf * 16];
                float4 f0 = sp[0], f1 = sp[1], f2 = sp[2], f3 = sp[3];
                p0[0] = f2b(f0.x); p0[1] = f2b(f0.y); p0[2] = f2b(f0.z); p0[3] = f2b(f0.w);
                p0[4] = f2b(f1.x); p0[5] = f2b(f1.y); p0[6] = f2b(f1.z); p0[7] = f2b(f1.w);
                p1[0] = f2b(f2.x); p1[1] = f2b(f2.y); p1[2] = f2b(f2.z); p1[3] = f2b(f2.w);
                p1[4] = f2b(f3.x); p1[5] = f2b(f3.y); p1[6] = f2b(f3.z); p1[7] = f2b(f3.w);
            } else {
                p0 = (ushort8)0; p1 = (ushort8)0;
            }
            *(ushort8*)&As[srow][shalf * 16] = p0;
            *(ushort8*)&As[srow][shalf * 16 + 8] = p1;
            const ushort8* bp = (const ushort8*)&Wt[(size_t)(c0 + srow) * 256 + k0 + shalf * 16];
            *(ushort8*)&Bs[srow][shalf * 16] = bp[0];
            *(ushort8*)&Bs[srow][shalf * 16 + 8] = bp[1];
        }
        __syncthreads();
        short8 af[4], bf[4];
#pragma unroll
        for (int i = 0; i < 4; i++)
            af[i] = *(const short8*)&As[rbw + i * 16 + lane15][quad * 8];
#pragma unroll
        for (int j = 0; j < 4; j++)
            bf[j] = *(const short8*)&Bs[cbw + j * 16 + lane15][quad * 8];
#pragma unroll
        for (int i = 0; i < 4; i++)
#pragma unroll
            for (int j = 0; j < 4; j++)
                acc[i][j] = __builtin_amdgcn_mfma_f32_16x16x32_bf16(af[i], bf[j], acc[i][j], 0, 0, 0);
        __syncthreads();
    }
#pragma unroll
    for (int i = 0; i < 4; i++) {
        int rowb = r0 + rbw + i * 16 + quad * 4;
#pragma unroll
        for (int j = 0; j < 4; j++) {
            int col = c0 + cbw + j * 16 + lane15;
#pragma unroll
            for (int r = 0; r < 4; r++) {
                int row = rowb + r;
                if (row < M) h1b[(size_t)row * 256 + col] = f2b(acc[i][j][r]);
            }
        }
    }
}

// ---------------- attention logits layer 1: wave per node, 4 nodes/block ----

__global__ __launch_bounds__(256) void k_al1(const unsigned short* __restrict__ h1b,
                                             const float* __restrict__ asrc,
                                             const float* __restrict__ adst,
                                             float* __restrict__ als,
                                             float* __restrict__ ald, int n) {
    int v = blockIdx.x * 4 + (threadIdx.x >> 6);
    if (v >= n) return;
    int lane = threadIdx.x & 63;      // cols lane*4..+3, head = lane>>3
    const uint2* hp = (const uint2*)(h1b + (size_t)v * 256);
    uint2 pk = hp[lane];
    float f0 = __uint_as_float(pk.x << 16);
    float f1 = __uint_as_float(pk.x & 0xffff0000u);
    float f2 = __uint_as_float(pk.y << 16);
    float f3 = __uint_as_float(pk.y & 0xffff0000u);
    float4 a_s = ((const float4*)asrc)[lane];
    float4 a_d = ((const float4*)adst)[lane];
    float ps = f0 * a_s.x + f1 * a_s.y + f2 * a_s.z + f3 * a_s.w;
    float pd = f0 * a_d.x + f1 * a_d.y + f2 * a_d.z + f3 * a_d.w;
#pragma unroll
    for (int off = 1; off < 8; off <<= 1) {
        ps += __shfl_xor(ps, off, 64);
        pd += __shfl_xor(pd, off, 64);
    }
    if ((lane & 7) == 0) {
        int h = lane >> 3;
        als[v * 8 + h] = ps;
        ald[v * 8 + h] = pd;
    }
}

// ---------------- layer-1 aggregate: fused weights, 128 thr/node ------------
// ws stride 33: write banks (t+h)%32 all-distinct, reads are broadcasts.

__global__ __launch_bounds__(128) void k_agg1(const int* __restrict__ csr,
                                              const int* __restrict__ offs,
                                              const float* __restrict__ als,
                                              const float* __restrict__ aldg,
                                              const unsigned short* __restrict__ h1b,
                                              const float* __restrict__ b1,
                                              unsigned short* __restrict__ x2b) {
    int v = blockIdx.x;
    int t = threadIdx.x;           // t in [0,128): cols 2t,2t+1; head = t>>4
    int start = offs[v];
    int deg = offs[v + 1] - start;
    __shared__ float aldv[8];
    __shared__ int su[32];
    __shared__ float ws[8 * 33];
    if (t < 8) aldv[t] = aldg[v * 8 + t];
    __syncthreads();
    int h = t >> 4;
    float a0 = 0.f, a1 = 0.f, wsum = 0.f;
    for (int base = 0; base < deg; base += 32) {
        int cnt = min(32, deg - base);
        if (base) __syncthreads();
        if (t < cnt) {
            int u = csr[start + base + t];
            su[t] = u;
            const float4* ap = (const float4*)(als + (size_t)u * 8);
            float4 x0 = ap[0], x1 = ap[1];
            ws[0 * 33 + t] = __expf(LRELU(x0.x + aldv[0]));
            ws[1 * 33 + t] = __expf(LRELU(x0.y + aldv[1]));
            ws[2 * 33 + t] = __expf(LRELU(x0.z + aldv[2]));
            ws[3 * 33 + t] = __expf(LRELU(x0.w + aldv[3]));
            ws[4 * 33 + t] = __expf(LRELU(x1.x + aldv[4]));
            ws[5 * 33 + t] = __expf(LRELU(x1.y + aldv[5]));
            ws[6 * 33 + t] = __expf(LRELU(x1.z + aldv[6]));
            ws[7 * 33 + t] = __expf(LRELU(x1.w + aldv[7]));
        }
        __syncthreads();
#pragma unroll 2
        for (int e = 0; e < cnt; e++) {
            float wv = ws[h * 33 + e];
            const unsigned int* hp = (const unsigned int*)(h1b + (size_t)su[e] * 256);
            unsigned int pk = hp[t];
            float f0 = __uint_as_float(pk << 16);
            float f1 = __uint_as_float(pk & 0xffff0000u);
            a0 += wv * f0;
            a1 += wv * f1;
            wsum += wv;
        }
    }
    const float2* b1v = (const float2*)b1;
    float2 bb = b1v[t];
    float inv = 1.0f / wsum;
    float o0 = a0 * inv + bb.x;
    float o1 = a1 * inv + bb.y;
    o0 = o0 > 0.f ? o0 : 0.f;
    o1 = o1 > 0.f ? o1 : 0.f;
    unsigned int opk = (unsigned int)f2b(o0) | ((unsigned int)f2b(o1) << 16);
    ((unsigned int*)(x2b + (size_t)v * 256))[t] = opk;
}

// ---------------- GEMM2 (MFMA) + fused layer-2 logits ----------------------
// 64 rows/block (4 waves x one 16x16 tile over K=256), h2 out bf16,
// als2/ald2 via width-16 xor-shuffle reduction.

__global__ __launch_bounds__(256) void k_gemm2(const unsigned short* __restrict__ Xb,
                                               const unsigned short* __restrict__ W2t,
                                               const float* __restrict__ asrc,
                                               const float* __restrict__ adst,
                                               unsigned short* __restrict__ h2b,
                                               float* __restrict__ als,
                                               float* __restrict__ ald, int n) {
    int t = threadIdx.x;
    int lane = t & 63, w = t >> 6;
    int lane15 = lane & 15, quad = lane >> 4;
    int row0 = blockIdx.x * 64 + w * 16;
    f32x4 acc = (f32x4)0.f;
#pragma unroll
    for (int k0 = 0; k0 < 256; k0 += 32) {
        short8 a = *(const short8*)&Xb[(size_t)(row0 + lane15) * 256 + k0 + quad * 8];
        short8 b = *(const short8*)&W2t[lane15 * 256 + k0 + quad * 8];
        acc = __builtin_amdgcn_mfma_f32_16x16x32_bf16(a, b, acc, 0, 0, 0);
    }
    float asv = asrc[lane15], adv = adst[lane15];
#pragma unroll
    for (int r = 0; r < 4; r++) {
        int row = row0 + quad * 4 + r;
        float hv = acc[r];
        float ps = hv * asv, pd = hv * adv;
#pragma unroll
        for (int off = 1; off < 16; off <<= 1) {
            ps += __shfl_xor(ps, off, 16);
            pd += __shfl_xor(pd, off, 16);
        }
        if (row < n) {
            h2b[(size_t)row * 16 + lane15] = f2b(hv);
            if (lane15 == 0) {
                als[row] = ps;
                ald[row] = pd;
            }
        }
    }
}

// ---------------- layer-2 aggregate (fused w) + log_softmax -----------------

__global__ __launch_bounds__(256) void k_agg2(const int* __restrict__ csr,
                                              const int* __restrict__ offs,
                                              const float* __restrict__ als,
                                              const float* __restrict__ aldg,
                                              const unsigned short* __restrict__ h2b,
                                              const float* __restrict__ b2,
                                              float* __restrict__ out, int n) {
    int v = blockIdx.x * 4 + (threadIdx.x >> 6);
    if (v >= n) return;
    int lane = threadIdx.x & 63;
    int start = offs[v];
    int deg = offs[v + 1] - start;
    float aldv = aldg[v];
    int c = lane & 15, q = lane >> 4;
    float acc = 0.f, wsum = 0.f;
    for (int e = q; e < deg; e += 4) {
        int u = csr[start + e];
        float x = als[u] + aldv;
        float wv = __expf(LRELU(x));
        acc += wv * b2f(h2b[(size_t)u * 16 + c]);
        wsum += wv;
    }
    acc += __shfl_xor(acc, 32, 64);
    acc += __shfl_xor(acc, 16, 64);
    wsum += __shfl_xor(wsum, 32, 64);
    wsum += __shfl_xor(wsum, 16, 64);
    float o = acc / wsum + b2[c];
    float mx = o;
#pragma unroll
    for (int off = 8; off; off >>= 1) mx = fmaxf(mx, __shfl_xor(mx, off, 16));
    float s = __expf(o - mx);
#pragma unroll
    for (int off = 8; off; off >>= 1) s += __shfl_xor(s, off, 16);
    float res = o - mx - __logf(s);
    if (q == 0) out[(size_t)v * 16 + c] = res;
}

// ---------------- launch ----------------

extern "C" void kernel_launch(void* const* d_in, const int* in_sizes, int n_in,
                              void* d_out, int out_size, void* d_ws, size_t ws_size,
                              hipStream_t stream) {
    const float* x = (const float*)d_in[0];
    const int* ei = (const int*)d_in[1];
    const float* W1 = (const float*)d_in[2];
    const float* asrc1 = (const float*)d_in[3];
    const float* adst1 = (const float*)d_in[4];
    const float* b1 = (const float*)d_in[5];
    const float* W2 = (const float*)d_in[6];
    const float* asrc2 = (const float*)d_in[7];
    const float* adst2 = (const float*)d_in[8];
    const float* b2 = (const float*)d_in[9];
    float* out = (float*)d_out;

    int n = in_sizes[0] / 256;   // 50000
    int E = in_sizes[1] / 2;     // 800000
    int P = E + n;
    const int* src = ei;
    const int* dst = ei + E;
    int NB = (n + 255) / 256;

    char* p = (char*)d_ws;
    auto alloc = [&](size_t bytes) {
        void* r = (void*)p;
        p += (bytes + 255) & ~(size_t)255;
        return r;
    };
    unsigned short* h1b = (unsigned short*)alloc((size_t)n * 256 * 2);
    unsigned short* x2b = (unsigned short*)alloc((size_t)n * 256 * 2);
    unsigned short* W1t = (unsigned short*)alloc((size_t)256 * 256 * 2);
    unsigned short* W2t = (unsigned short*)alloc((size_t)16 * 256 * 2);
    float* als1 = (float*)alloc((size_t)n * 8 * 4);
    float* ald1 = (float*)alloc((size_t)n * 8 * 4);
    unsigned short* h2b = (unsigned short*)alloc((size_t)n * 16 * 2);
    float* als2 = (float*)alloc((size_t)n * 4);
    float* ald2 = (float*)alloc((size_t)n * 4);
    int* deg = (int*)alloc((size_t)n * 4);
    int* offs = (int*)alloc((size_t)(n + 1) * 4);
    int* cursor = (int*)alloc((size_t)n * 4);
    int* stmp = (int*)alloc((size_t)n * 4);
    int* blocksum = (int*)alloc((size_t)NB * 4);
    int* blockpre = (int*)alloc((size_t)NB * 4);
    int* csr = (int*)alloc((size_t)P * 4);

    // CSR build
    hipMemsetAsync(deg, 0, (size_t)n * 4, stream);
    k_hist<<<(E + 255) / 256, 256, 0, stream>>>(dst, deg, E);
    k_scanA<<<NB, 256, 0, stream>>>(deg, stmp, blocksum, n);
    k_scanB<<<1, 256, 0, stream>>>(blocksum, blockpre, NB);
    k_scanC<<<NB, 256, 0, stream>>>(stmp, blockpre, offs, cursor, n, P);
    k_scatter<<<(P + 255) / 256, 256, 0, stream>>>(src, dst, cursor, csr, E, n);

    // layer 1
    k_prepw<<<256, 256, 0, stream>>>(W1, W1t);
    k_prepw2<<<16, 256, 0, stream>>>(W2, W2t);
    k_gemm1<<<dim3((n + 127) / 128, 2), 256, 0, stream>>>(x, W1t, h1b, n);
    k_al1<<<(n + 3) / 4, 256, 0, stream>>>(h1b, asrc1, adst1, als1, ald1, n);
    k_agg1<<<n, 128, 0, stream>>>(csr, offs, als1, ald1, h1b, b1, x2b);

    // layer 2
    k_gemm2<<<(n + 63) / 64, 256, 0, stream>>>(x2b, W2t, asrc2, adst2, h2b, als2, ald2, n);
    k_agg2<<<(n + 3) / 4, 256, 0, stream>>>(csr, offs, als2, ald2, h2b, b2, out, n);
}

// Round 9
// 333.360 us; speedup vs baseline: 2.2678x; 1.0317x over previous
//
#include <hip/hip_runtime.h>
#include <hip/hip_bf16.h>

// GATNet v8: k_agg1 with explicit 4-deep gather pipelining (v7's unroll-2
// pragma capped memory-level parallelism: VGPR 24->16, 82.8us; v6 conflicted
// but 4-deep was 68us — this version has both conflict-free ws AND 4 in flight).

#define LRELU(x) ((x) > 0.f ? (x) : 0.2f * (x))

typedef __attribute__((ext_vector_type(8))) short short8;
typedef __attribute__((ext_vector_type(8))) unsigned short ushort8;
typedef __attribute__((ext_vector_type(4))) float f32x4;

__device__ inline unsigned short f2b(float f) {
    __hip_bfloat16 h = __float2bfloat16(f);
    return *reinterpret_cast<unsigned short*>(&h);
}
__device__ inline float b2f(unsigned short u) {
    __hip_bfloat16 h;
    *reinterpret_cast<unsigned short*>(&h) = u;
    return __bfloat162float(h);
}

// ---------------- CSR build ----------------

__global__ void k_hist(const int* __restrict__ dst, int* deg, int E) {
    int i = blockIdx.x * blockDim.x + threadIdx.x;
    if (i < E) atomicAdd(&deg[dst[i]], 1);
}

__global__ __launch_bounds__(256) void k_scanA(const int* __restrict__ deg,
                                               int* __restrict__ tmp,
                                               int* __restrict__ blocksum, int n) {
    __shared__ int sc[256];
    int b = blockIdx.x, t = threadIdx.x;
    int i = b * 256 + t;
    int v = (i < n) ? deg[i] + 1 : 0;   // +1: self loop
    sc[t] = v;
    __syncthreads();
    for (int off = 1; off < 256; off <<= 1) {
        int x = 0;
        if (t >= off) x = sc[t - off];
        __syncthreads();
        sc[t] += x;
        __syncthreads();
    }
    if (i < n) tmp[i] = sc[t] - v;
    if (t == 255) blocksum[b] = sc[255];
}

__global__ __launch_bounds__(256) void k_scanB(const int* __restrict__ blocksum,
                                               int* __restrict__ blockpre, int nb) {
    __shared__ int sc[256];
    int t = threadIdx.x;
    int v = (t < nb) ? blocksum[t] : 0;
    sc[t] = v;
    __syncthreads();
    for (int off = 1; off < 256; off <<= 1) {
        int x = 0;
        if (t >= off) x = sc[t - off];
        __syncthreads();
        sc[t] += x;
        __syncthreads();
    }
    if (t < nb) blockpre[t] = sc[t] - v;
}

__global__ __launch_bounds__(256) void k_scanC(const int* __restrict__ tmp,
                                               const int* __restrict__ blockpre,
                                               int* __restrict__ offs,
                                               int* __restrict__ cursor, int n, int P) {
    int b = blockIdx.x, t = threadIdx.x;
    int i = b * 256 + t;
    if (i < n) {
        int o = tmp[i] + blockpre[b];
        offs[i] = o;
        cursor[i] = o;
    }
    if (i == 0) offs[n] = P;
}

__global__ void k_scatter(const int* __restrict__ src, const int* __restrict__ dst,
                          int* cursor, int* __restrict__ csr, int E, int n) {
    int i = blockIdx.x * blockDim.x + threadIdx.x;
    int s, d;
    if (i < E) {
        s = src[i];
        d = dst[i];
    } else if (i < E + n) {
        s = i - E;
        d = s;
    } else {
        return;
    }
    int p = atomicAdd(&cursor[d], 1);
    csr[p] = s;
}

// ---------------- weight prep: W1t[256][256], W2t[16][256] bf16 -------------

__global__ __launch_bounds__(256) void k_prepw(const float* __restrict__ W,
                                               unsigned short* __restrict__ Wt) {
    int k = blockIdx.x;
    int nn = threadIdx.x;
    Wt[nn * 256 + k] = f2b(W[k * 256 + nn]);
}

__global__ __launch_bounds__(256) void k_prepw2(const float* __restrict__ W,
                                                unsigned short* __restrict__ Wt) {
    int nn = blockIdx.x;  // 16
    int k = threadIdx.x;  // 256
    Wt[nn * 256 + k] = f2b(W[k * 16 + nn]);
}

// ---------------- GEMM1 (MFMA bf16): h1b[M,256] = bf16(A[M,256] @ W1) -------

__global__ __launch_bounds__(256) void k_gemm1(const float* __restrict__ A,
                                               const unsigned short* __restrict__ Wt,
                                               unsigned short* __restrict__ h1b, int M) {
    __shared__ unsigned short As[128][40];
    __shared__ unsigned short Bs[128][40];
    int t = threadIdx.x;
    int r0 = blockIdx.x * 128, c0 = blockIdx.y * 128;
    int srow = t >> 1, shalf = t & 1;
    int lane = t & 63, w = t >> 6;
    int lane15 = lane & 15, quad = lane >> 4;
    int rbw = (w & 1) * 64, cbw = (w >> 1) * 64;

    f32x4 acc[4][4];
#pragma unroll
    for (int i = 0; i < 4; i++)
#pragma unroll
        for (int j = 0; j < 4; j++) acc[i][j] = (f32x4)0.f;

    for (int k0 = 0; k0 < 256; k0 += 32) {
        {
            int row = r0 + srow;
            ushort8 p0, p1;
            if (row < M) {
                const float4* sp = (const float4*)&A[(size_t)row * 256 + k0 + shalf * 16];
                float4 f0 = sp[0], f1 = sp[1], f2 = sp[2], f3 = sp[3];
                p0[0] = f2b(f0.x); p0[1] = f2b(f0.y); p0[2] = f2b(f0.z); p0[3] = f2b(f0.w);
                p0[4] = f2b(f1.x); p0[5] = f2b(f1.y); p0[6] = f2b(f1.z); p0[7] = f2b(f1.w);
                p1[0] = f2b(f2.x); p1[1] = f2b(f2.y); p1[2] = f2b(f2.z); p1[3] = f2b(f2.w);
                p1[4] = f2b(f3.x); p1[5] = f2b(f3.y); p1[6] = f2b(f3.z); p1[7] = f2b(f3.w);
            } else {
                p0 = (ushort8)0; p1 = (ushort8)0;
            }
            *(ushort8*)&As[srow][shalf * 16] = p0;
            *(ushort8*)&As[srow][shalf * 16 + 8] = p1;
            const ushort8* bp = (const ushort8*)&Wt[(size_t)(c0 + srow) * 256 + k0 + shalf * 16];
            *(ushort8*)&Bs[srow][shalf * 16] = bp[0];
            *(ushort8*)&Bs[srow][shalf * 16 + 8] = bp[1];
        }
        __syncthreads();
        short8 af[4], bf[4];
#pragma unroll
        for (int i = 0; i < 4; i++)
            af[i] = *(const short8*)&As[rbw + i * 16 + lane15][quad * 8];
#pragma unroll
        for (int j = 0; j < 4; j++)
            bf[j] = *(const short8*)&Bs[cbw + j * 16 + lane15][quad * 8];
#pragma unroll
        for (int i = 0; i < 4; i++)
#pragma unroll
            for (int j = 0; j < 4; j++)
                acc[i][j] = __builtin_amdgcn_mfma_f32_16x16x32_bf16(af[i], bf[j], acc[i][j], 0, 0, 0);
        __syncthreads();
    }
#pragma unroll
    for (int i = 0; i < 4; i++) {
        int rowb = r0 + rbw + i * 16 + quad * 4;
#pragma unroll
        for (int j = 0; j < 4; j++) {
            int col = c0 + cbw + j * 16 + lane15;
#pragma unroll
            for (int r = 0; r < 4; r++) {
                int row = rowb + r;
                if (row < M) h1b[(size_t)row * 256 + col] = f2b(acc[i][j][r]);
            }
        }
    }
}

// ---------------- attention logits layer 1: wave per node, 4 nodes/block ----

__global__ __launch_bounds__(256) void k_al1(const unsigned short* __restrict__ h1b,
                                             const float* __restrict__ asrc,
                                             const float* __restrict__ adst,
                                             float* __restrict__ als,
                                             float* __restrict__ ald, int n) {
    int v = blockIdx.x * 4 + (threadIdx.x >> 6);
    if (v >= n) return;
    int lane = threadIdx.x & 63;
    const uint2* hp = (const uint2*)(h1b + (size_t)v * 256);
    uint2 pk = hp[lane];
    float f0 = __uint_as_float(pk.x << 16);
    float f1 = __uint_as_float(pk.x & 0xffff0000u);
    float f2 = __uint_as_float(pk.y << 16);
    float f3 = __uint_as_float(pk.y & 0xffff0000u);
    float4 a_s = ((const float4*)asrc)[lane];
    float4 a_d = ((const float4*)adst)[lane];
    float ps = f0 * a_s.x + f1 * a_s.y + f2 * a_s.z + f3 * a_s.w;
    float pd = f0 * a_d.x + f1 * a_d.y + f2 * a_d.z + f3 * a_d.w;
#pragma unroll
    for (int off = 1; off < 8; off <<= 1) {
        ps += __shfl_xor(ps, off, 64);
        pd += __shfl_xor(pd, off, 64);
    }
    if ((lane & 7) == 0) {
        int h = lane >> 3;
        als[v * 8 + h] = ps;
        ald[v * 8 + h] = pd;
    }
}

// ---------------- layer-1 aggregate: fused weights, 4-deep gather pipeline --

__global__ __launch_bounds__(128) void k_agg1(const int* __restrict__ csr,
                                              const int* __restrict__ offs,
                                              const float* __restrict__ als,
                                              const float* __restrict__ aldg,
                                              const unsigned short* __restrict__ h1b,
                                              const float* __restrict__ b1,
                                              unsigned short* __restrict__ x2b) {
    int v = blockIdx.x;
    int t = threadIdx.x;           // cols 2t,2t+1; head = t>>4
    int start = offs[v];
    int deg = offs[v + 1] - start;
    __shared__ float aldv[8];
    __shared__ int su[32];
    __shared__ float ws[8 * 33];
    if (t < 8) aldv[t] = aldg[v * 8 + t];
    __syncthreads();
    int h = t >> 4;
    const unsigned int* __restrict__ hbase = (const unsigned int*)h1b;
    float a0 = 0.f, a1 = 0.f, wsum = 0.f;
    for (int base = 0; base < deg; base += 32) {
        int cnt = min(32, deg - base);
        int cnt4 = (cnt + 3) & ~3;      // pad to multiple of 4 (<=32)
        if (base) __syncthreads();
        if (t < cnt4) {
            if (t < cnt) {
                int u = csr[start + base + t];
                su[t] = u;
                const float4* ap = (const float4*)(als + (size_t)u * 8);
                float4 x0 = ap[0], x1 = ap[1];
                ws[0 * 33 + t] = __expf(LRELU(x0.x + aldv[0]));
                ws[1 * 33 + t] = __expf(LRELU(x0.y + aldv[1]));
                ws[2 * 33 + t] = __expf(LRELU(x0.z + aldv[2]));
                ws[3 * 33 + t] = __expf(LRELU(x0.w + aldv[3]));
                ws[4 * 33 + t] = __expf(LRELU(x1.x + aldv[4]));
                ws[5 * 33 + t] = __expf(LRELU(x1.y + aldv[5]));
                ws[6 * 33 + t] = __expf(LRELU(x1.z + aldv[6]));
                ws[7 * 33 + t] = __expf(LRELU(x1.w + aldv[7]));
            } else {
                su[t] = v;   // valid row, weight 0 -> inert
#pragma unroll
                for (int k = 0; k < 8; k++) ws[k * 33 + t] = 0.f;
            }
        }
        __syncthreads();
        for (int e = 0; e < cnt4; e += 4) {
            int u0 = su[e + 0], u1 = su[e + 1], u2 = su[e + 2], u3 = su[e + 3];
            float w0 = ws[h * 33 + e + 0];
            float w1 = ws[h * 33 + e + 1];
            float w2 = ws[h * 33 + e + 2];
            float w3 = ws[h * 33 + e + 3];
            unsigned int pk0 = hbase[u0 * 128 + t];
            unsigned int pk1 = hbase[u1 * 128 + t];
            unsigned int pk2 = hbase[u2 * 128 + t];
            unsigned int pk3 = hbase[u3 * 128 + t];
            a0 += w0 * __uint_as_float(pk0 << 16);
            a1 += w0 * __uint_as_float(pk0 & 0xffff0000u);
            a0 += w1 * __uint_as_float(pk1 << 16);
            a1 += w1 * __uint_as_float(pk1 & 0xffff0000u);
            a0 += w2 * __uint_as_float(pk2 << 16);
            a1 += w2 * __uint_as_float(pk2 & 0xffff0000u);
            a0 += w3 * __uint_as_float(pk3 << 16);
            a1 += w3 * __uint_as_float(pk3 & 0xffff0000u);
            wsum += (w0 + w1) + (w2 + w3);
        }
    }
    const float2* b1v = (const float2*)b1;
    float2 bb = b1v[t];
    float inv = 1.0f / wsum;
    float o0 = a0 * inv + bb.x;
    float o1 = a1 * inv + bb.y;
    o0 = o0 > 0.f ? o0 : 0.f;
    o1 = o1 > 0.f ? o1 : 0.f;
    unsigned int opk = (unsigned int)f2b(o0) | ((unsigned int)f2b(o1) << 16);
    ((unsigned int*)(x2b + (size_t)v * 256))[t] = opk;
}

// ---------------- GEMM2 (MFMA) + fused layer-2 logits ----------------------

__global__ __launch_bounds__(256) void k_gemm2(const unsigned short* __restrict__ Xb,
                                               const unsigned short* __restrict__ W2t,
                                               const float* __restrict__ asrc,
                                               const float* __restrict__ adst,
                                               unsigned short* __restrict__ h2b,
                                               float* __restrict__ als,
                                               float* __restrict__ ald, int n) {
    int t = threadIdx.x;
    int lane = t & 63, w = t >> 6;
    int lane15 = lane & 15, quad = lane >> 4;
    int row0 = blockIdx.x * 64 + w * 16;
    f32x4 acc = (f32x4)0.f;
#pragma unroll
    for (int k0 = 0; k0 < 256; k0 += 32) {
        short8 a = *(const short8*)&Xb[(size_t)(row0 + lane15) * 256 + k0 + quad * 8];
        short8 b = *(const short8*)&W2t[lane15 * 256 + k0 + quad * 8];
        acc = __builtin_amdgcn_mfma_f32_16x16x32_bf16(a, b, acc, 0, 0, 0);
    }
    float asv = asrc[lane15], adv = adst[lane15];
#pragma unroll
    for (int r = 0; r < 4; r++) {
        int row = row0 + quad * 4 + r;
        float hv = acc[r];
        float ps = hv * asv, pd = hv * adv;
#pragma unroll
        for (int off = 1; off < 16; off <<= 1) {
            ps += __shfl_xor(ps, off, 16);
            pd += __shfl_xor(pd, off, 16);
        }
        if (row < n) {
            h2b[(size_t)row * 16 + lane15] = f2b(hv);
            if (lane15 == 0) {
                als[row] = ps;
                ald[row] = pd;
            }
        }
    }
}

// ---------------- layer-2 aggregate (fused w) + log_softmax -----------------

__global__ __launch_bounds__(256) void k_agg2(const int* __restrict__ csr,
                                              const int* __restrict__ offs,
                                              const float* __restrict__ als,
                                              const float* __restrict__ aldg,
                                              const unsigned short* __restrict__ h2b,
                                              const float* __restrict__ b2,
                                              float* __restrict__ out, int n) {
    int v = blockIdx.x * 4 + (threadIdx.x >> 6);
    if (v >= n) return;
    int lane = threadIdx.x & 63;
    int start = offs[v];
    int deg = offs[v + 1] - start;
    float aldv = aldg[v];
    int c = lane & 15, q = lane >> 4;
    float acc = 0.f, wsum = 0.f;
    for (int e = q; e < deg; e += 4) {
        int u = csr[start + e];
        float x = als[u] + aldv;
        float wv = __expf(LRELU(x));
        acc += wv * b2f(h2b[(size_t)u * 16 + c]);
        wsum += wv;
    }
    acc += __shfl_xor(acc, 32, 64);
    acc += __shfl_xor(acc, 16, 64);
    wsum += __shfl_xor(wsum, 32, 64);
    wsum += __shfl_xor(wsum, 16, 64);
    float o = acc / wsum + b2[c];
    float mx = o;
#pragma unroll
    for (int off = 8; off; off >>= 1) mx = fmaxf(mx, __shfl_xor(mx, off, 16));
    float s = __expf(o - mx);
#pragma unroll
    for (int off = 8; off; off >>= 1) s += __shfl_xor(s, off, 16);
    float res = o - mx - __logf(s);
    if (q == 0) out[(size_t)v * 16 + c] = res;
}

// ---------------- launch ----------------

extern "C" void kernel_launch(void* const* d_in, const int* in_sizes, int n_in,
                              void* d_out, int out_size, void* d_ws, size_t ws_size,
                              hipStream_t stream) {
    const float* x = (const float*)d_in[0];
    const int* ei = (const int*)d_in[1];
    const float* W1 = (const float*)d_in[2];
    const float* asrc1 = (const float*)d_in[3];
    const float* adst1 = (const float*)d_in[4];
    const float* b1 = (const float*)d_in[5];
    const float* W2 = (const float*)d_in[6];
    const float* asrc2 = (const float*)d_in[7];
    const float* adst2 = (const float*)d_in[8];
    const float* b2 = (const float*)d_in[9];
    float* out = (float*)d_out;

    int n = in_sizes[0] / 256;   // 50000
    int E = in_sizes[1] / 2;     // 800000
    int P = E + n;
    const int* src = ei;
    const int* dst = ei + E;
    int NB = (n + 255) / 256;

    char* p = (char*)d_ws;
    auto alloc = [&](size_t bytes) {
        void* r = (void*)p;
        p += (bytes + 255) & ~(size_t)255;
        return r;
    };
    unsigned short* h1b = (unsigned short*)alloc((size_t)n * 256 * 2);
    unsigned short* x2b = (unsigned short*)alloc((size_t)n * 256 * 2);
    unsigned short* W1t = (unsigned short*)alloc((size_t)256 * 256 * 2);
    unsigned short* W2t = (unsigned short*)alloc((size_t)16 * 256 * 2);
    float* als1 = (float*)alloc((size_t)n * 8 * 4);
    float* ald1 = (float*)alloc((size_t)n * 8 * 4);
    unsigned short* h2b = (unsigned short*)alloc((size_t)n * 16 * 2);
    float* als2 = (float*)alloc((size_t)n * 4);
    float* ald2 = (float*)alloc((size_t)n * 4);
    int* deg = (int*)alloc((size_t)n * 4);
    int* offs = (int*)alloc((size_t)(n + 1) * 4);
    int* cursor = (int*)alloc((size_t)n * 4);
    int* stmp = (int*)alloc((size_t)n * 4);
    int* blocksum = (int*)alloc((size_t)NB * 4);
    int* blockpre = (int*)alloc((size_t)NB * 4);
    int* csr = (int*)alloc((size_t)P * 4);

    // CSR build
    hipMemsetAsync(deg, 0, (size_t)n * 4, stream);
    k_hist<<<(E + 255) / 256, 256, 0, stream>>>(dst, deg, E);
    k_scanA<<<NB, 256, 0, stream>>>(deg, stmp, blocksum, n);
    k_scanB<<<1, 256, 0, stream>>>(blocksum, blockpre, NB);
    k_scanC<<<NB, 256, 0, stream>>>(stmp, blockpre, offs, cursor, n, P);
    k_scatter<<<(P + 255) / 256, 256, 0, stream>>>(src, dst, cursor, csr, E, n);

    // layer 1
    k_prepw<<<256, 256, 0, stream>>>(W1, W1t);
    k_prepw2<<<16, 256, 0, stream>>>(W2, W2t);
    k_gemm1<<<dim3((n + 127) / 128, 2), 256, 0, stream>>>(x, W1t, h1b, n);
    k_al1<<<(n + 3) / 4, 256, 0, stream>>>(h1b, asrc1, adst1, als1, ald1, n);
    k_agg1<<<n, 128, 0, stream>>>(csr, offs, als1, ald1, h1b, b1, x2b);

    // layer 2
    k_gemm2<<<(n + 63) / 64, 256, 0, stream>>>(x2b, W2t, asrc2, adst2, h2b, als2, ald2, n);
    k_agg2<<<(n + 3) / 4, 256, 0, stream>>>(csr, offs, als2, ald2, h2b, b2, out, n);
}